// Round 1
// baseline (1677.811 us; speedup 1.0000x reference)
//
#include <hip/hip_runtime.h>
#include <hip/hip_bf16.h>

#define CH 128          // HID_CH == OUT_CH == 128
#define IN_CH_K 512

// ---------------- degree kernels ----------------
__global__ void init_deg_kernel(float* deg, int n) {
    int i = blockIdx.x * blockDim.x + threadIdx.x;
    if (i < n) deg[i] = 1.0f;   // self-loop contributes 1
}

__global__ void count_deg_kernel(const int* __restrict__ dst, float* __restrict__ deg, int E) {
    int i = blockIdx.x * blockDim.x + threadIdx.x;
    int stride = gridDim.x * blockDim.x;
    for (int e = i; e < E; e += stride)
        atomicAdd(&deg[dst[e]], 1.0f);
}

__global__ void rsqrt_kernel(float* deg, int n) {
    int i = blockIdx.x * blockDim.x + threadIdx.x;
    if (i < n) deg[i] = rsqrtf(deg[i]);
}

// ---------------- GEMM: C[M][128] = act(A)[M][K] @ B[K][128] ----------------
// 64x128 tile per block, 256 threads, each thread computes 8x4.
template<int K, bool RELU>
__launch_bounds__(256)
__global__ void gemm_nn_kernel(const float* __restrict__ A, const float* __restrict__ B,
                               float* __restrict__ C, int M) {
    __shared__ float As[16][64];    // [k][row]
    __shared__ float Bs[16][128];   // [k][col]

    const int tid = threadIdx.x;
    const int block_row = blockIdx.x * 64;

    const int tr = tid >> 5;        // 0..7  (row group of 8)
    const int tc = tid & 31;        // 0..31 (col group of 4)

    // A loader: thread -> (row in tile, k offset)
    const int la_r = tid >> 2;          // 0..63
    const int la_c = (tid & 3) * 4;     // 0,4,8,12
    // B loader: thread -> (k row, col offset)
    const int lb_r = tid >> 4;          // 0..15
    const int lb_c = (tid & 15) * 8;    // 0..120

    float acc[8][4];
    #pragma unroll
    for (int i = 0; i < 8; ++i)
        #pragma unroll
        for (int j = 0; j < 4; ++j) acc[i][j] = 0.0f;

    for (int k0 = 0; k0 < K; k0 += 16) {
        // ---- stage A tile ----
        int arow = block_row + la_r;
        float4 av;
        if (arow < M) {
            av = *reinterpret_cast<const float4*>(&A[(size_t)arow * K + k0 + la_c]);
        } else {
            av = make_float4(0.f, 0.f, 0.f, 0.f);
        }
        if (RELU) {
            av.x = fmaxf(av.x, 0.f); av.y = fmaxf(av.y, 0.f);
            av.z = fmaxf(av.z, 0.f); av.w = fmaxf(av.w, 0.f);
        }
        As[la_c + 0][la_r] = av.x;
        As[la_c + 1][la_r] = av.y;
        As[la_c + 2][la_r] = av.z;
        As[la_c + 3][la_r] = av.w;

        // ---- stage B tile ----
        const float4* bp = reinterpret_cast<const float4*>(&B[(size_t)(k0 + lb_r) * CH + lb_c]);
        float4 b0 = bp[0], b1 = bp[1];
        *reinterpret_cast<float4*>(&Bs[lb_r][lb_c])     = b0;
        *reinterpret_cast<float4*>(&Bs[lb_r][lb_c + 4]) = b1;

        __syncthreads();

        #pragma unroll
        for (int kk = 0; kk < 16; ++kk) {
            float a[8], b[4];
            float4 a0 = *reinterpret_cast<const float4*>(&As[kk][tr * 8]);
            float4 a1 = *reinterpret_cast<const float4*>(&As[kk][tr * 8 + 4]);
            a[0]=a0.x; a[1]=a0.y; a[2]=a0.z; a[3]=a0.w;
            a[4]=a1.x; a[5]=a1.y; a[6]=a1.z; a[7]=a1.w;
            float4 bv = *reinterpret_cast<const float4*>(&Bs[kk][tc * 4]);
            b[0]=bv.x; b[1]=bv.y; b[2]=bv.z; b[3]=bv.w;
            #pragma unroll
            for (int i = 0; i < 8; ++i)
                #pragma unroll
                for (int j = 0; j < 4; ++j)
                    acc[i][j] = fmaf(a[i], b[j], acc[i][j]);
        }
        __syncthreads();
    }

    #pragma unroll
    for (int i = 0; i < 8; ++i) {
        int row = block_row + tr * 8 + i;
        if (row < M) {
            float4 v = make_float4(acc[i][0], acc[i][1], acc[i][2], acc[i][3]);
            *reinterpret_cast<float4*>(&C[(size_t)row * CH + tc * 4]) = v;
        }
    }
}

// ---------------- self-loop + bias init: out[i][c] = h[i][c]*dinv[i]^2 + b[c] ----------------
__global__ void selfloop_bias_kernel(const float* __restrict__ h, const float* __restrict__ dinv,
                                     const float* __restrict__ b, float* __restrict__ out, int n) {
    int i = blockIdx.x * blockDim.x + threadIdx.x;   // one float4 per thread
    int total = n * (CH / 4);
    if (i >= total) return;
    int node = i >> 5;                  // CH/4 == 32
    int c4 = (i & 31) * 4;
    float s = dinv[node];
    s = s * s;
    float4 hv = *reinterpret_cast<const float4*>(&h[(size_t)node * CH + c4]);
    float4 bv = *reinterpret_cast<const float4*>(&b[c4]);
    float4 o;
    o.x = hv.x * s + bv.x;
    o.y = hv.y * s + bv.y;
    o.z = hv.z * s + bv.z;
    o.w = hv.w * s + bv.w;
    *reinterpret_cast<float4*>(&out[(size_t)node * CH + c4]) = o;
}

// ---------------- edge scatter: out[dst] += h[src] * dinv[src]*dinv[dst] ----------------
__global__ void scatter_kernel(const int* __restrict__ src, const int* __restrict__ dst,
                               const float* __restrict__ h, const float* __restrict__ dinv,
                               float* __restrict__ out, int E) {
    const int c = threadIdx.x & (CH - 1);     // channel 0..127
    const int sub = threadIdx.x >> 7;         // 0 or 1 (2 edges per block per iter)
    const int step = gridDim.x * 2;
    for (int e = blockIdx.x * 2 + sub; e < E; e += step) {
        int s = src[e];
        int d = dst[e];
        float nrm = dinv[s] * dinv[d];
        float v = h[(size_t)s * CH + c] * nrm;
        atomicAdd(&out[(size_t)d * CH + c], v);
    }
}

extern "C" void kernel_launch(void* const* d_in, const int* in_sizes, int n_in,
                              void* d_out, int out_size, void* d_ws, size_t ws_size,
                              hipStream_t stream) {
    const float* x  = (const float*)d_in[0];
    const int*   ei = (const int*)d_in[1];
    const float* W1 = (const float*)d_in[2];
    const float* b1 = (const float*)d_in[3];
    const float* W2 = (const float*)d_in[4];
    const float* b2 = (const float*)d_in[5];
    float* out = (float*)d_out;

    const int N = in_sizes[0] / IN_CH_K;       // 100000
    const int E = in_sizes[1] / 2;             // 1600000
    const int* e_src = ei;
    const int* e_dst = ei + E;

    // workspace layout: deg/dinv [N] | bufA [N*128] | bufB [N*128]
    float* deg  = (float*)d_ws;
    float* bufA = deg + (((size_t)N + 255) & ~(size_t)255);
    float* bufB = bufA + (size_t)N * CH;

    // ---- degrees ----
    init_deg_kernel<<<(N + 255) / 256, 256, 0, stream>>>(deg, N);
    count_deg_kernel<<<2048, 256, 0, stream>>>(e_dst, deg, E);
    rsqrt_kernel<<<(N + 255) / 256, 256, 0, stream>>>(deg, N);

    const int gemm_grid = (N + 63) / 64;
    const int sb_grid = (N * (CH / 4) + 255) / 256;

    // ---- layer 1: h1 = x @ W1 ----
    gemm_nn_kernel<IN_CH_K, false><<<gemm_grid, 256, 0, stream>>>(x, W1, bufA, N);
    // agg1 = h1*dinv^2 + b1 (self-loop + bias)
    selfloop_bias_kernel<<<sb_grid, 256, 0, stream>>>(bufA, deg, b1, bufB, N);
    // agg1 += scatter(h1)
    scatter_kernel<<<16384, 256, 0, stream>>>(e_src, e_dst, bufA, deg, bufB, E);

    // ---- layer 2: h2 = relu(agg1) @ W2 ----
    gemm_nn_kernel<CH, true><<<gemm_grid, 256, 0, stream>>>(bufB, W2, bufA, N);
    // out = h2*dinv^2 + b2
    selfloop_bias_kernel<<<sb_grid, 256, 0, stream>>>(bufA, deg, b2, out, N);
    // out += scatter(h2)
    scatter_kernel<<<16384, 256, 0, stream>>>(e_src, e_dst, bufA, deg, out, E);
}

// Round 2
// 696.754 us; speedup vs baseline: 2.4080x; 2.4080x over previous
//
#include <hip/hip_runtime.h>
#include <hip/hip_bf16.h>

#define CH 128          // HID_CH == OUT_CH == 128
#define IN_CH_K 512

// ---------------- CSR build ----------------
__global__ void zero_int_kernel(int* __restrict__ p, int n) {
    int i = blockIdx.x * blockDim.x + threadIdx.x;
    if (i < n) p[i] = 0;
}

__global__ void count_kernel(const int* __restrict__ dst, int* __restrict__ cnt, int E) {
    int i = blockIdx.x * blockDim.x + threadIdx.x;
    int stride = gridDim.x * blockDim.x;
    for (int e = i; e < E; e += stride)
        atomicAdd(&cnt[dst[e]], 1);
}

__global__ void dinv_kernel(const int* __restrict__ cnt, float* __restrict__ dinv, int n) {
    int i = blockIdx.x * blockDim.x + threadIdx.x;
    if (i < n) dinv[i] = rsqrtf((float)(cnt[i] + 1));   // +1 self-loop
}

// exclusive scan, 256 elems/block
__global__ void scan1_kernel(const int* __restrict__ cnt, int* __restrict__ row_off,
                             int* __restrict__ bsums, int n) {
    __shared__ int tmp[256];
    const int tid = threadIdx.x;
    const int i = blockIdx.x * 256 + tid;
    int v = (i < n) ? cnt[i] : 0;
    tmp[tid] = v;
    __syncthreads();
    #pragma unroll
    for (int off = 1; off < 256; off <<= 1) {
        int t = (tid >= off) ? tmp[tid - off] : 0;
        __syncthreads();
        tmp[tid] += t;
        __syncthreads();
    }
    if (i < n) row_off[i] = tmp[tid] - v;      // exclusive within block
    if (tid == 255) bsums[blockIdx.x] = tmp[255];
}

__global__ void scan2_kernel(int* __restrict__ bsums, int nb) {
    __shared__ int tmp[512];
    const int tid = threadIdx.x;
    int v = (tid < nb) ? bsums[tid] : 0;
    tmp[tid] = v;
    __syncthreads();
    #pragma unroll
    for (int off = 1; off < 512; off <<= 1) {
        int t = (tid >= off) ? tmp[tid - off] : 0;
        __syncthreads();
        tmp[tid] += t;
        __syncthreads();
    }
    if (tid < nb) bsums[tid] = tmp[tid] - v;   // exclusive
}

__global__ void scan3_kernel(int* __restrict__ row_off, int* __restrict__ cursor,
                             const int* __restrict__ bsums, int n, int E) {
    const int i = blockIdx.x * 256 + threadIdx.x;
    if (i < n) {
        int r = row_off[i] + bsums[blockIdx.x];
        row_off[i] = r;
        cursor[i] = r;
    }
    if (i == 0) row_off[n] = E;
}

__global__ void fill_kernel(const int* __restrict__ src, const int* __restrict__ dst,
                            int* __restrict__ cursor, int* __restrict__ csr_src, int E) {
    int i = blockIdx.x * blockDim.x + threadIdx.x;
    int stride = gridDim.x * blockDim.x;
    for (int e = i; e < E; e += stride) {
        int d = dst[e];
        int pos = atomicAdd(&cursor[d], 1);
        csr_src[pos] = src[e];
    }
}

// ---------------- GEMM: C[M][128] = act(A)[M][K] @ B[K][128], scaled by dinv[row] ----------------
// 64x128 tile per block, 256 threads, each thread computes 8x4.
template<int K, bool RELU>
__launch_bounds__(256)
__global__ void gemm_scale_kernel(const float* __restrict__ A, const float* __restrict__ B,
                                  const float* __restrict__ dinv, float* __restrict__ C, int M) {
    __shared__ float As[16][64];    // [k][row]
    __shared__ float Bs[16][128];   // [k][col]

    const int tid = threadIdx.x;
    const int block_row = blockIdx.x * 64;

    const int tr = tid >> 5;        // 0..7
    const int tc = tid & 31;        // 0..31

    const int la_r = tid >> 2;          // 0..63
    const int la_c = (tid & 3) * 4;     // 0,4,8,12
    const int lb_r = tid >> 4;          // 0..15
    const int lb_c = (tid & 15) * 8;    // 0..120

    float acc[8][4];
    #pragma unroll
    for (int i = 0; i < 8; ++i)
        #pragma unroll
        for (int j = 0; j < 4; ++j) acc[i][j] = 0.0f;

    for (int k0 = 0; k0 < K; k0 += 16) {
        int arow = block_row + la_r;
        float4 av;
        if (arow < M) {
            av = *reinterpret_cast<const float4*>(&A[(size_t)arow * K + k0 + la_c]);
        } else {
            av = make_float4(0.f, 0.f, 0.f, 0.f);
        }
        if (RELU) {
            av.x = fmaxf(av.x, 0.f); av.y = fmaxf(av.y, 0.f);
            av.z = fmaxf(av.z, 0.f); av.w = fmaxf(av.w, 0.f);
        }
        As[la_c + 0][la_r] = av.x;
        As[la_c + 1][la_r] = av.y;
        As[la_c + 2][la_r] = av.z;
        As[la_c + 3][la_r] = av.w;

        const float4* bp = reinterpret_cast<const float4*>(&B[(size_t)(k0 + lb_r) * CH + lb_c]);
        float4 b0 = bp[0], b1 = bp[1];
        *reinterpret_cast<float4*>(&Bs[lb_r][lb_c])     = b0;
        *reinterpret_cast<float4*>(&Bs[lb_r][lb_c + 4]) = b1;

        __syncthreads();

        #pragma unroll
        for (int kk = 0; kk < 16; ++kk) {
            float a[8], b[4];
            float4 a0 = *reinterpret_cast<const float4*>(&As[kk][tr * 8]);
            float4 a1 = *reinterpret_cast<const float4*>(&As[kk][tr * 8 + 4]);
            a[0]=a0.x; a[1]=a0.y; a[2]=a0.z; a[3]=a0.w;
            a[4]=a1.x; a[5]=a1.y; a[6]=a1.z; a[7]=a1.w;
            float4 bv = *reinterpret_cast<const float4*>(&Bs[kk][tc * 4]);
            b[0]=bv.x; b[1]=bv.y; b[2]=bv.z; b[3]=bv.w;
            #pragma unroll
            for (int i = 0; i < 8; ++i)
                #pragma unroll
                for (int j = 0; j < 4; ++j)
                    acc[i][j] = fmaf(a[i], b[j], acc[i][j]);
        }
        __syncthreads();
    }

    #pragma unroll
    for (int i = 0; i < 8; ++i) {
        int row = block_row + tr * 8 + i;
        if (row < M) {
            float s = dinv[row];
            float4 v = make_float4(acc[i][0] * s, acc[i][1] * s, acc[i][2] * s, acc[i][3] * s);
            *reinterpret_cast<float4*>(&C[(size_t)row * CH + tc * 4]) = v;
        }
    }
}

// ---------------- aggregation: out[d] = dinv[d]*(g[d] + sum_{in-edges} g[src]) + bias ----------------
// one wave (64 lanes) per node; 2 channels per lane (float2 = 8B, 512B/row coalesced)
__launch_bounds__(256)
__global__ void aggregate_kernel(const float* __restrict__ g, const int* __restrict__ row_off,
                                 const int* __restrict__ csr_src, const float* __restrict__ dinv,
                                 const float* __restrict__ bias, float* __restrict__ out, int N) {
    const int gtid = blockIdx.x * blockDim.x + threadIdx.x;
    const int node = gtid >> 6;
    if (node >= N) return;
    const int lane = threadIdx.x & 63;
    const int c = lane * 2;

    float2 acc = *reinterpret_cast<const float2*>(&g[(size_t)node * CH + c]);  // self-loop term

    const int beg = row_off[node];
    const int end = row_off[node + 1];
    int j = beg;
    for (; j + 4 <= end; j += 4) {
        int s0 = __builtin_amdgcn_readfirstlane(csr_src[j]);
        int s1 = __builtin_amdgcn_readfirstlane(csr_src[j + 1]);
        int s2 = __builtin_amdgcn_readfirstlane(csr_src[j + 2]);
        int s3 = __builtin_amdgcn_readfirstlane(csr_src[j + 3]);
        float2 v0 = *reinterpret_cast<const float2*>(&g[(size_t)s0 * CH + c]);
        float2 v1 = *reinterpret_cast<const float2*>(&g[(size_t)s1 * CH + c]);
        float2 v2 = *reinterpret_cast<const float2*>(&g[(size_t)s2 * CH + c]);
        float2 v3 = *reinterpret_cast<const float2*>(&g[(size_t)s3 * CH + c]);
        acc.x += (v0.x + v1.x) + (v2.x + v3.x);
        acc.y += (v0.y + v1.y) + (v2.y + v3.y);
    }
    for (; j < end; ++j) {
        int s = __builtin_amdgcn_readfirstlane(csr_src[j]);
        float2 v = *reinterpret_cast<const float2*>(&g[(size_t)s * CH + c]);
        acc.x += v.x;
        acc.y += v.y;
    }

    const float di = dinv[node];
    float2 bv = *reinterpret_cast<const float2*>(&bias[c]);
    float2 o;
    o.x = di * acc.x + bv.x;
    o.y = di * acc.y + bv.y;
    *reinterpret_cast<float2*>(&out[(size_t)node * CH + c]) = o;
}

extern "C" void kernel_launch(void* const* d_in, const int* in_sizes, int n_in,
                              void* d_out, int out_size, void* d_ws, size_t ws_size,
                              hipStream_t stream) {
    const float* x  = (const float*)d_in[0];
    const int*   ei = (const int*)d_in[1];
    const float* W1 = (const float*)d_in[2];
    const float* b1 = (const float*)d_in[3];
    const float* W2 = (const float*)d_in[4];
    const float* b2 = (const float*)d_in[5];
    float* out = (float*)d_out;

    const int N = in_sizes[0] / IN_CH_K;       // 100000
    const int E = in_sizes[1] / 2;             // 1600000
    const int* e_src = ei;
    const int* e_dst = ei + E;

    const int nblk256 = (N + 255) / 256;       // 391

    // workspace layout (all 256B aligned):
    char* w = (char*)d_ws;
    auto alloc = [&](size_t bytes) {
        char* p = w;
        w += (bytes + 255) & ~(size_t)255;
        return p;
    };
    int*   cnt     = (int*)  alloc((size_t)N * 4);
    int*   row_off = (int*)  alloc(((size_t)N + 1) * 4);
    int*   cursor  = (int*)  alloc((size_t)N * 4);
    int*   bsums   = (int*)  alloc(512 * 4);
    float* dinv    = (float*)alloc((size_t)N * 4);
    int*   csr_src = (int*)  alloc((size_t)E * 4);
    float* bufA    = (float*)alloc((size_t)N * CH * 4);

    // ---- CSR build + degrees ----
    zero_int_kernel<<<nblk256, 256, 0, stream>>>(cnt, N);
    count_kernel<<<2048, 256, 0, stream>>>(e_dst, cnt, E);
    dinv_kernel<<<nblk256, 256, 0, stream>>>(cnt, dinv, N);
    scan1_kernel<<<nblk256, 256, 0, stream>>>(cnt, row_off, bsums, N);
    scan2_kernel<<<1, 512, 0, stream>>>(bsums, nblk256);
    scan3_kernel<<<nblk256, 256, 0, stream>>>(row_off, cursor, bsums, N, E);
    fill_kernel<<<2048, 256, 0, stream>>>(e_src, e_dst, cursor, csr_src, E);

    const int gemm_grid = (N + 63) / 64;
    const int agg_grid = (N * 64 + 255) / 256;   // one wave per node

    // ---- layer 1 ----
    // g1 = (x @ W1) * dinv[row]
    gemm_scale_kernel<IN_CH_K, false><<<gemm_grid, 256, 0, stream>>>(x, W1, dinv, bufA, N);
    // a1 = dinv*(g1[self] + sum g1[src]) + b1   -> stored in d_out (scratch)
    aggregate_kernel<<<agg_grid, 256, 0, stream>>>(bufA, row_off, csr_src, dinv, b1, out, N);

    // ---- layer 2 ----
    // g2 = (relu(a1) @ W2) * dinv[row]
    gemm_scale_kernel<CH, true><<<gemm_grid, 256, 0, stream>>>(out, W2, dinv, bufA, N);
    // out = dinv*(g2[self] + sum g2[src]) + b2
    aggregate_kernel<<<agg_grid, 256, 0, stream>>>(bufA, row_off, csr_src, dinv, b2, out, N);
}

// Round 3
// 551.297 us; speedup vs baseline: 3.0434x; 1.2638x over previous
//
#include <hip/hip_runtime.h>
#include <hip/hip_bf16.h>

#define CH 128          // HID_CH == OUT_CH == 128
#define IN_CH_K 512

typedef short s16x8 __attribute__((ext_vector_type(8)));   // 8 bf16 (4 VGPRs)
typedef float f32x4 __attribute__((ext_vector_type(4)));

__device__ __forceinline__ unsigned short f2bf(float f) {
    unsigned int u = __builtin_bit_cast(unsigned int, f);
    unsigned int r = (u + 0x7fffu + ((u >> 16) & 1u)) >> 16;
    return (unsigned short)r;
}

// ---------------- CSR build ----------------
__global__ void zero_int_kernel(int* __restrict__ p, int n) {
    int i = blockIdx.x * blockDim.x + threadIdx.x;
    if (i < n) p[i] = 0;
}

__global__ void count_kernel(const int* __restrict__ dst, int* __restrict__ cnt, int E) {
    int i = blockIdx.x * blockDim.x + threadIdx.x;
    int stride = gridDim.x * blockDim.x;
    for (int e = i; e < E; e += stride)
        atomicAdd(&cnt[dst[e]], 1);
}

__global__ void dinv_kernel(const int* __restrict__ cnt, float* __restrict__ dinv, int n) {
    int i = blockIdx.x * blockDim.x + threadIdx.x;
    if (i < n) dinv[i] = rsqrtf((float)(cnt[i] + 1));   // +1 self-loop
}

// exclusive scan, 256 elems/block
__global__ void scan1_kernel(const int* __restrict__ cnt, int* __restrict__ row_off,
                             int* __restrict__ bsums, int n) {
    __shared__ int tmp[256];
    const int tid = threadIdx.x;
    const int i = blockIdx.x * 256 + tid;
    int v = (i < n) ? cnt[i] : 0;
    tmp[tid] = v;
    __syncthreads();
    #pragma unroll
    for (int off = 1; off < 256; off <<= 1) {
        int t = (tid >= off) ? tmp[tid - off] : 0;
        __syncthreads();
        tmp[tid] += t;
        __syncthreads();
    }
    if (i < n) row_off[i] = tmp[tid] - v;
    if (tid == 255) bsums[blockIdx.x] = tmp[255];
}

__global__ void scan2_kernel(int* __restrict__ bsums, int nb) {
    __shared__ int tmp[512];
    const int tid = threadIdx.x;
    int v = (tid < nb) ? bsums[tid] : 0;
    tmp[tid] = v;
    __syncthreads();
    #pragma unroll
    for (int off = 1; off < 512; off <<= 1) {
        int t = (tid >= off) ? tmp[tid - off] : 0;
        __syncthreads();
        tmp[tid] += t;
        __syncthreads();
    }
    if (tid < nb) bsums[tid] = tmp[tid] - v;
}

__global__ void scan3_kernel(int* __restrict__ row_off, int* __restrict__ cursor,
                             const int* __restrict__ bsums, int n, int E) {
    const int i = blockIdx.x * 256 + threadIdx.x;
    if (i < n) {
        int r = row_off[i] + bsums[blockIdx.x];
        row_off[i] = r;
        cursor[i] = r;
    }
    if (i == 0) row_off[n] = E;
}

__global__ void fill_kernel(const int* __restrict__ src, const int* __restrict__ dst,
                            int* __restrict__ cursor, int* __restrict__ csr_src, int E) {
    int i = blockIdx.x * blockDim.x + threadIdx.x;
    int stride = gridDim.x * blockDim.x;
    for (int e = i; e < E; e += stride) {
        int d = dst[e];
        int pos = atomicAdd(&cursor[d], 1);
        csr_src[pos] = src[e];
    }
}

// ---------------- weight pre-transpose to MFMA B-fragment layout ----------------
// WT[g*128 + col] (uint4 = 8 bf16) holds W[g*8+j][col], j=0..7
__global__ void convert_w_kernel(const float* __restrict__ W, uint4* __restrict__ WT, int K) {
    int i = blockIdx.x * blockDim.x + threadIdx.x;
    int ng = K >> 3;
    if (i >= ng * CH) return;
    int g = i >> 7;
    int col = i & 127;
    unsigned int h[8];
    #pragma unroll
    for (int j = 0; j < 8; ++j) h[j] = f2bf(W[(size_t)(g * 8 + j) * CH + col]);
    uint4 v;
    v.x = h[0] | (h[1] << 16);
    v.y = h[2] | (h[3] << 16);
    v.z = h[4] | (h[5] << 16);
    v.w = h[6] | (h[7] << 16);
    WT[i] = v;
}

// ---------------- MFMA GEMM: C[M][128] = (act(A)[M][K] @ W[K][128]) * dinv[row] ----------------
// LDS-free: A-fragments loaded coalesced from f32 A and converted in-register;
// B-fragments loaded from pre-transposed bf16 WT (L2-resident).
// 256 threads = 4 waves; wave w owns rows w*32..w*32+31 (2 m-frags) x 128 cols (8 n-frags).
template<int K, bool RELU>
__launch_bounds__(256)
__global__ void gemm_mfma_kernel(const float* __restrict__ A, const uint4* __restrict__ WT,
                                 const float* __restrict__ dinv, float* __restrict__ C, int M) {
    const int tid = threadIdx.x;
    const int wid = tid >> 6;
    const int lane = tid & 63;
    const int l15 = lane & 15;
    const int lg = lane >> 4;          // 0..3 (k-group within 32-wide K step)

    const int block_row = blockIdx.x * 128 + wid * 32;

    f32x4 acc[2][8];
    #pragma unroll
    for (int m = 0; m < 2; ++m)
        #pragma unroll
        for (int n = 0; n < 8; ++n)
            acc[m][n] = (f32x4){0.f, 0.f, 0.f, 0.f};

    // clamped A rows (row mixing never crosses rows in GEMM; OOB rows not stored)
    int arow0 = block_row + l15;        // m = 0
    int arow1 = block_row + 16 + l15;   // m = 1
    arow0 = (arow0 < M) ? arow0 : (M - 1);
    arow1 = (arow1 < M) ? arow1 : (M - 1);
    const float* aptr0 = A + (size_t)arow0 * K + lg * 8;
    const float* aptr1 = A + (size_t)arow1 * K + lg * 8;

    for (int k0 = 0; k0 < K; k0 += 32) {
        // ---- A fragments: 32B f32 per lane -> 8 bf16 ----
        s16x8 afrag[2];
        #pragma unroll
        for (int m = 0; m < 2; ++m) {
            const float* ap = (m == 0 ? aptr0 : aptr1) + k0;
            float4 f0 = *reinterpret_cast<const float4*>(ap);
            float4 f1 = *reinterpret_cast<const float4*>(ap + 4);
            if (RELU) {
                f0.x = fmaxf(f0.x, 0.f); f0.y = fmaxf(f0.y, 0.f);
                f0.z = fmaxf(f0.z, 0.f); f0.w = fmaxf(f0.w, 0.f);
                f1.x = fmaxf(f1.x, 0.f); f1.y = fmaxf(f1.y, 0.f);
                f1.z = fmaxf(f1.z, 0.f); f1.w = fmaxf(f1.w, 0.f);
            }
            s16x8 a;
            a[0] = (short)f2bf(f0.x); a[1] = (short)f2bf(f0.y);
            a[2] = (short)f2bf(f0.z); a[3] = (short)f2bf(f0.w);
            a[4] = (short)f2bf(f1.x); a[5] = (short)f2bf(f1.y);
            a[6] = (short)f2bf(f1.z); a[7] = (short)f2bf(f1.w);
            afrag[m] = a;
        }

        // ---- B fragments + MFMA ----
        const int gbase = (k0 >> 3) + lg;
        #pragma unroll
        for (int n = 0; n < 8; ++n) {
            uint4 bv = WT[(size_t)gbase * CH + n * 16 + l15];
            s16x8 b = __builtin_bit_cast(s16x8, bv);
            acc[0][n] = __builtin_amdgcn_mfma_f32_16x16x32_bf16(afrag[0], b, acc[0][n], 0, 0, 0);
            acc[1][n] = __builtin_amdgcn_mfma_f32_16x16x32_bf16(afrag[1], b, acc[1][n], 0, 0, 0);
        }
    }

    // ---- epilogue: D[row=(lg)*4+i][col=l15] per frag; scale by dinv[row] ----
    #pragma unroll
    for (int m = 0; m < 2; ++m) {
        #pragma unroll
        for (int i = 0; i < 4; ++i) {
            int row = block_row + m * 16 + lg * 4 + i;
            if (row < M) {
                float s = dinv[row];
                #pragma unroll
                for (int n = 0; n < 8; ++n) {
                    C[(size_t)row * CH + n * 16 + l15] = acc[m][n][i] * s;
                }
            }
        }
    }
}

// ---------------- aggregation: out[d] = dinv[d]*(g[d] + sum_{in-edges} g[src]) + bias ----------------
__launch_bounds__(256)
__global__ void aggregate_kernel(const float* __restrict__ g, const int* __restrict__ row_off,
                                 const int* __restrict__ csr_src, const float* __restrict__ dinv,
                                 const float* __restrict__ bias, float* __restrict__ out, int N) {
    const int gtid = blockIdx.x * blockDim.x + threadIdx.x;
    const int node = gtid >> 6;
    if (node >= N) return;
    const int lane = threadIdx.x & 63;
    const int c = lane * 2;

    float2 acc = *reinterpret_cast<const float2*>(&g[(size_t)node * CH + c]);  // self-loop

    const int beg = row_off[node];
    const int end = row_off[node + 1];
    int j = beg;
    for (; j + 4 <= end; j += 4) {
        int s0 = __builtin_amdgcn_readfirstlane(csr_src[j]);
        int s1 = __builtin_amdgcn_readfirstlane(csr_src[j + 1]);
        int s2 = __builtin_amdgcn_readfirstlane(csr_src[j + 2]);
        int s3 = __builtin_amdgcn_readfirstlane(csr_src[j + 3]);
        float2 v0 = *reinterpret_cast<const float2*>(&g[(size_t)s0 * CH + c]);
        float2 v1 = *reinterpret_cast<const float2*>(&g[(size_t)s1 * CH + c]);
        float2 v2 = *reinterpret_cast<const float2*>(&g[(size_t)s2 * CH + c]);
        float2 v3 = *reinterpret_cast<const float2*>(&g[(size_t)s3 * CH + c]);
        acc.x += (v0.x + v1.x) + (v2.x + v3.x);
        acc.y += (v0.y + v1.y) + (v2.y + v3.y);
    }
    for (; j < end; ++j) {
        int s = __builtin_amdgcn_readfirstlane(csr_src[j]);
        float2 v = *reinterpret_cast<const float2*>(&g[(size_t)s * CH + c]);
        acc.x += v.x;
        acc.y += v.y;
    }

    const float di = dinv[node];
    float2 bv = *reinterpret_cast<const float2*>(&bias[c]);
    float2 o;
    o.x = di * acc.x + bv.x;
    o.y = di * acc.y + bv.y;
    *reinterpret_cast<float2*>(&out[(size_t)node * CH + c]) = o;
}

extern "C" void kernel_launch(void* const* d_in, const int* in_sizes, int n_in,
                              void* d_out, int out_size, void* d_ws, size_t ws_size,
                              hipStream_t stream) {
    const float* x  = (const float*)d_in[0];
    const int*   ei = (const int*)d_in[1];
    const float* W1 = (const float*)d_in[2];
    const float* b1 = (const float*)d_in[3];
    const float* W2 = (const float*)d_in[4];
    const float* b2 = (const float*)d_in[5];
    float* out = (float*)d_out;

    const int N = in_sizes[0] / IN_CH_K;       // 100000
    const int E = in_sizes[1] / 2;             // 1600000
    const int* e_src = ei;
    const int* e_dst = ei + E;

    const int nblk256 = (N + 255) / 256;

    char* w = (char*)d_ws;
    auto alloc = [&](size_t bytes) {
        char* p = w;
        w += (bytes + 255) & ~(size_t)255;
        return p;
    };
    int*   cnt     = (int*)  alloc((size_t)N * 4);
    int*   row_off = (int*)  alloc(((size_t)N + 1) * 4);
    int*   cursor  = (int*)  alloc((size_t)N * 4);
    int*   bsums   = (int*)  alloc(512 * 4);
    float* dinv    = (float*)alloc((size_t)N * 4);
    int*   csr_src = (int*)  alloc((size_t)E * 4);
    uint4* w1t     = (uint4*)alloc((size_t)(IN_CH_K / 8) * CH * 16);
    uint4* w2t     = (uint4*)alloc((size_t)(CH / 8) * CH * 16);
    float* bufA    = (float*)alloc((size_t)N * CH * 4);

    // ---- CSR build + degrees + weight conversion ----
    zero_int_kernel<<<nblk256, 256, 0, stream>>>(cnt, N);
    count_kernel<<<2048, 256, 0, stream>>>(e_dst, cnt, E);
    dinv_kernel<<<nblk256, 256, 0, stream>>>(cnt, dinv, N);
    scan1_kernel<<<nblk256, 256, 0, stream>>>(cnt, row_off, bsums, N);
    scan2_kernel<<<1, 512, 0, stream>>>(bsums, nblk256);
    scan3_kernel<<<nblk256, 256, 0, stream>>>(row_off, cursor, bsums, N, E);
    fill_kernel<<<2048, 256, 0, stream>>>(e_src, e_dst, cursor, csr_src, E);
    convert_w_kernel<<<(IN_CH_K / 8 * CH + 255) / 256, 256, 0, stream>>>(W1, w1t, IN_CH_K);
    convert_w_kernel<<<(CH / 8 * CH + 255) / 256, 256, 0, stream>>>(W2, w2t, CH);

    const int gemm_grid = (N + 127) / 128;
    const int agg_grid = (N * 64 + 255) / 256;

    // ---- layer 1 ----
    gemm_mfma_kernel<IN_CH_K, false><<<gemm_grid, 256, 0, stream>>>(x, w1t, dinv, bufA, N);
    aggregate_kernel<<<agg_grid, 256, 0, stream>>>(bufA, row_off, csr_src, dinv, b1, out, N);

    // ---- layer 2 ----
    gemm_mfma_kernel<CH, true><<<gemm_grid, 256, 0, stream>>>(out, w2t, dinv, bufA, N);
    aggregate_kernel<<<agg_grid, 256, 0, stream>>>(bufA, row_off, csr_src, dinv, b2, out, N);
}

// Round 4
// 415.178 us; speedup vs baseline: 4.0412x; 1.3279x over previous
//
#include <hip/hip_runtime.h>
#include <hip/hip_bf16.h>

#define CH 128          // HID_CH == OUT_CH == 128
#define IN_CH_K 512
#define CHUNK 8192      // edges per bucket-sort block

typedef short s16x8 __attribute__((ext_vector_type(8)));   // 8 bf16 (4 VGPRs)
typedef float f32x4 __attribute__((ext_vector_type(4)));

__device__ __forceinline__ unsigned short f2bf(float f) {
    unsigned int u = __builtin_bit_cast(unsigned int, f);
    unsigned int r = (u + 0x7fffu + ((u >> 16) & 1u)) >> 16;
    return (unsigned short)r;
}

// ---------------- bucket-sort CSR build ----------------
__global__ void zero_int_kernel(int* __restrict__ p, int n) {
    int i = blockIdx.x * blockDim.x + threadIdx.x;
    if (i < n) p[i] = 0;
}

// k1: per-chunk LDS histogram over coarse buckets (dst>>8), merged via global adds
__global__ void bucket_count_kernel(const int* __restrict__ dst, int* __restrict__ bucket_cnt,
                                    int E, int NB) {
    __shared__ int h[512];
    for (int i = threadIdx.x; i < NB; i += 256) h[i] = 0;
    __syncthreads();
    const int beg = blockIdx.x * CHUNK;
    const int end = min(E, beg + CHUNK);
    for (int e = beg + threadIdx.x; e < end; e += 256)
        atomicAdd(&h[dst[e] >> 8], 1);
    __syncthreads();
    for (int i = threadIdx.x; i < NB; i += 256)
        if (h[i]) atomicAdd(&bucket_cnt[i], h[i]);
}

// k2: exclusive scan of bucket counts (NB <= 512), init cursors
__global__ void bucket_scan_kernel(const int* __restrict__ bucket_cnt, int* __restrict__ bucket_base,
                                   int* __restrict__ bucket_cursor, int NB, int E) {
    __shared__ int tmp[512];
    const int tid = threadIdx.x;
    int v = (tid < NB) ? bucket_cnt[tid] : 0;
    tmp[tid] = v;
    __syncthreads();
    #pragma unroll
    for (int off = 1; off < 512; off <<= 1) {
        int t = (tid >= off) ? tmp[tid - off] : 0;
        __syncthreads();
        tmp[tid] += t;
        __syncthreads();
    }
    int ex = tmp[tid] - v;
    if (tid < NB) { bucket_base[tid] = ex; bucket_cursor[tid] = ex; }
    if (tid == 0) bucket_base[NB] = E;
}

// k3: bin edges into bucket regions; per-edge cursors in LDS, one global atomic per (block,bucket)
__global__ void bin_kernel(const int* __restrict__ src, const int* __restrict__ dst,
                           int* __restrict__ bucket_cursor, int* __restrict__ binned,
                           int E, int NB) {
    __shared__ int h[512];
    __shared__ int base[512];
    __shared__ int cur[512];
    for (int i = threadIdx.x; i < NB; i += 256) h[i] = 0;
    __syncthreads();
    const int beg = blockIdx.x * CHUNK;
    const int end = min(E, beg + CHUNK);
    for (int e = beg + threadIdx.x; e < end; e += 256)
        atomicAdd(&h[dst[e] >> 8], 1);
    __syncthreads();
    for (int i = threadIdx.x; i < NB; i += 256) {
        cur[i] = 0;
        if (h[i]) base[i] = atomicAdd(&bucket_cursor[i], h[i]);
    }
    __syncthreads();
    for (int e = beg + threadIdx.x; e < end; e += 256) {
        int d = dst[e];
        int b = d >> 8;
        int r = atomicAdd(&cur[b], 1);
        binned[base[b] + r] = src[e] | ((d & 255) << 17);   // src < 2^17
    }
}

// k4: per-bucket (256 nodes) CSR finalize: row_off, dinv, csr_src; all per-edge atomics in LDS
__global__ void csr_bucket_kernel(const int* __restrict__ binned, const int* __restrict__ bucket_base,
                                  int* __restrict__ row_off, int* __restrict__ csr_src,
                                  float* __restrict__ dinv, int N, int E) {
    __shared__ int cnt[256];
    __shared__ int off[256];
    __shared__ int cur[256];
    const int k = blockIdx.x;
    const int t = threadIdx.x;
    cnt[t] = 0;
    __syncthreads();
    const int beg = bucket_base[k];
    const int end = bucket_base[k + 1];
    for (int e = beg + t; e < end; e += 256)
        atomicAdd(&cnt[binned[e] >> 17], 1);
    __syncthreads();
    int v = cnt[t];
    off[t] = v;
    __syncthreads();
    #pragma unroll
    for (int o = 1; o < 256; o <<= 1) {
        int tv = (t >= o) ? off[t - o] : 0;
        __syncthreads();
        off[t] += tv;
        __syncthreads();
    }
    int ex = off[t] - v;   // exclusive prefix within bucket
    int node = k * 256 + t;
    if (node < N) {
        row_off[node] = beg + ex;
        dinv[node] = rsqrtf((float)(v + 1));   // +1 self-loop
    }
    cur[t] = ex;
    __syncthreads();
    for (int e = beg + t; e < end; e += 256) {
        int p = binned[e];
        int dl = p >> 17;
        int r = atomicAdd(&cur[dl], 1);
        csr_src[beg + r] = p & 0x1FFFF;
    }
    if (k == 0 && t == 0) row_off[N] = E;
}

// ---------------- weight pre-transpose to MFMA B-fragment layout ----------------
__global__ void convert_w_kernel(const float* __restrict__ W, uint4* __restrict__ WT, int K) {
    int i = blockIdx.x * blockDim.x + threadIdx.x;
    int ng = K >> 3;
    if (i >= ng * CH) return;
    int g = i >> 7;
    int col = i & 127;
    unsigned int h[8];
    #pragma unroll
    for (int j = 0; j < 8; ++j) h[j] = f2bf(W[(size_t)(g * 8 + j) * CH + col]);
    uint4 v;
    v.x = h[0] | (h[1] << 16);
    v.y = h[2] | (h[3] << 16);
    v.z = h[4] | (h[5] << 16);
    v.w = h[6] | (h[7] << 16);
    WT[i] = v;
}

// ---------------- MFMA GEMM: C[M][128] = (act(A)[M][K] @ W[K][128]) * dinv[row] ----------------
template<int K, bool RELU>
__launch_bounds__(256)
__global__ void gemm_mfma_kernel(const float* __restrict__ A, const uint4* __restrict__ WT,
                                 const float* __restrict__ dinv, float* __restrict__ C, int M) {
    const int tid = threadIdx.x;
    const int wid = tid >> 6;
    const int lane = tid & 63;
    const int l15 = lane & 15;
    const int lg = lane >> 4;          // 0..3

    const int block_row = blockIdx.x * 128 + wid * 32;

    f32x4 acc[2][8];
    #pragma unroll
    for (int m = 0; m < 2; ++m)
        #pragma unroll
        for (int n = 0; n < 8; ++n)
            acc[m][n] = (f32x4){0.f, 0.f, 0.f, 0.f};

    int arow0 = block_row + l15;
    int arow1 = block_row + 16 + l15;
    arow0 = (arow0 < M) ? arow0 : (M - 1);
    arow1 = (arow1 < M) ? arow1 : (M - 1);
    const float* aptr0 = A + (size_t)arow0 * K + lg * 8;
    const float* aptr1 = A + (size_t)arow1 * K + lg * 8;

    for (int k0 = 0; k0 < K; k0 += 32) {
        s16x8 afrag[2];
        #pragma unroll
        for (int m = 0; m < 2; ++m) {
            const float* ap = (m == 0 ? aptr0 : aptr1) + k0;
            float4 f0 = *reinterpret_cast<const float4*>(ap);
            float4 f1 = *reinterpret_cast<const float4*>(ap + 4);
            if (RELU) {
                f0.x = fmaxf(f0.x, 0.f); f0.y = fmaxf(f0.y, 0.f);
                f0.z = fmaxf(f0.z, 0.f); f0.w = fmaxf(f0.w, 0.f);
                f1.x = fmaxf(f1.x, 0.f); f1.y = fmaxf(f1.y, 0.f);
                f1.z = fmaxf(f1.z, 0.f); f1.w = fmaxf(f1.w, 0.f);
            }
            s16x8 a;
            a[0] = (short)f2bf(f0.x); a[1] = (short)f2bf(f0.y);
            a[2] = (short)f2bf(f0.z); a[3] = (short)f2bf(f0.w);
            a[4] = (short)f2bf(f1.x); a[5] = (short)f2bf(f1.y);
            a[6] = (short)f2bf(f1.z); a[7] = (short)f2bf(f1.w);
            afrag[m] = a;
        }

        const int gbase = (k0 >> 3) + lg;
        #pragma unroll
        for (int n = 0; n < 8; ++n) {
            uint4 bv = WT[(size_t)gbase * CH + n * 16 + l15];
            s16x8 b = __builtin_bit_cast(s16x8, bv);
            acc[0][n] = __builtin_amdgcn_mfma_f32_16x16x32_bf16(afrag[0], b, acc[0][n], 0, 0, 0);
            acc[1][n] = __builtin_amdgcn_mfma_f32_16x16x32_bf16(afrag[1], b, acc[1][n], 0, 0, 0);
        }
    }

    #pragma unroll
    for (int m = 0; m < 2; ++m) {
        #pragma unroll
        for (int i = 0; i < 4; ++i) {
            int row = block_row + m * 16 + lg * 4 + i;
            if (row < M) {
                float s = dinv[row];
                #pragma unroll
                for (int n = 0; n < 8; ++n) {
                    C[(size_t)row * CH + n * 16 + l15] = acc[m][n][i] * s;
                }
            }
        }
    }
}

// ---------------- aggregation: out[d] = dinv[d]*(g[d] + sum_{in-edges} g[src]) + bias ----------------
__launch_bounds__(256)
__global__ void aggregate_kernel(const float* __restrict__ g, const int* __restrict__ row_off,
                                 const int* __restrict__ csr_src, const float* __restrict__ dinv,
                                 const float* __restrict__ bias, float* __restrict__ out, int N) {
    const int gtid = blockIdx.x * blockDim.x + threadIdx.x;
    const int node = gtid >> 6;
    if (node >= N) return;
    const int lane = threadIdx.x & 63;
    const int c = lane * 2;

    float2 acc = *reinterpret_cast<const float2*>(&g[(size_t)node * CH + c]);  // self-loop

    const int beg = row_off[node];
    const int end = row_off[node + 1];
    int j = beg;
    for (; j + 4 <= end; j += 4) {
        int s0 = __builtin_amdgcn_readfirstlane(csr_src[j]);
        int s1 = __builtin_amdgcn_readfirstlane(csr_src[j + 1]);
        int s2 = __builtin_amdgcn_readfirstlane(csr_src[j + 2]);
        int s3 = __builtin_amdgcn_readfirstlane(csr_src[j + 3]);
        float2 v0 = *reinterpret_cast<const float2*>(&g[(size_t)s0 * CH + c]);
        float2 v1 = *reinterpret_cast<const float2*>(&g[(size_t)s1 * CH + c]);
        float2 v2 = *reinterpret_cast<const float2*>(&g[(size_t)s2 * CH + c]);
        float2 v3 = *reinterpret_cast<const float2*>(&g[(size_t)s3 * CH + c]);
        acc.x += (v0.x + v1.x) + (v2.x + v3.x);
        acc.y += (v0.y + v1.y) + (v2.y + v3.y);
    }
    for (; j < end; ++j) {
        int s = __builtin_amdgcn_readfirstlane(csr_src[j]);
        float2 v = *reinterpret_cast<const float2*>(&g[(size_t)s * CH + c]);
        acc.x += v.x;
        acc.y += v.y;
    }

    const float di = dinv[node];
    float2 bv = *reinterpret_cast<const float2*>(&bias[c]);
    float2 o;
    o.x = di * acc.x + bv.x;
    o.y = di * acc.y + bv.y;
    *reinterpret_cast<float2*>(&out[(size_t)node * CH + c]) = o;
}

extern "C" void kernel_launch(void* const* d_in, const int* in_sizes, int n_in,
                              void* d_out, int out_size, void* d_ws, size_t ws_size,
                              hipStream_t stream) {
    const float* x  = (const float*)d_in[0];
    const int*   ei = (const int*)d_in[1];
    const float* W1 = (const float*)d_in[2];
    const float* b1 = (const float*)d_in[3];
    const float* W2 = (const float*)d_in[4];
    const float* b2 = (const float*)d_in[5];
    float* out = (float*)d_out;

    const int N = in_sizes[0] / IN_CH_K;       // 100000
    const int E = in_sizes[1] / 2;             // 1600000
    const int* e_src = ei;
    const int* e_dst = ei + E;

    const int NB = (N + 255) >> 8;             // 391 coarse buckets
    const int NCHUNK = (E + CHUNK - 1) / CHUNK;

    char* w = (char*)d_ws;
    auto alloc = [&](size_t bytes) {
        char* p = w;
        w += (bytes + 255) & ~(size_t)255;
        return p;
    };
    int*   bucket_cnt    = (int*)  alloc((size_t)NB * 4);
    int*   bucket_base   = (int*)  alloc(((size_t)NB + 1) * 4);
    int*   bucket_cursor = (int*)  alloc((size_t)NB * 4);
    int*   row_off       = (int*)  alloc(((size_t)N + 1) * 4);
    float* dinv          = (float*)alloc((size_t)N * 4);
    int*   csr_src       = (int*)  alloc((size_t)E * 4);
    uint4* w1t           = (uint4*)alloc((size_t)(IN_CH_K / 8) * CH * 16);
    uint4* w2t           = (uint4*)alloc((size_t)(CH / 8) * CH * 16);
    float* bufA          = (float*)alloc((size_t)N * CH * 4);
    int*   binned        = (int*)bufA;   // aliases bufA: dead before gemm1 writes bufA

    // ---- CSR build (bucket sort) + weight conversion ----
    zero_int_kernel<<<(NB + 255) / 256, 256, 0, stream>>>(bucket_cnt, NB);
    bucket_count_kernel<<<NCHUNK, 256, 0, stream>>>(e_dst, bucket_cnt, E, NB);
    bucket_scan_kernel<<<1, 512, 0, stream>>>(bucket_cnt, bucket_base, bucket_cursor, NB, E);
    bin_kernel<<<NCHUNK, 256, 0, stream>>>(e_src, e_dst, bucket_cursor, binned, E, NB);
    csr_bucket_kernel<<<NB, 256, 0, stream>>>(binned, bucket_base, row_off, csr_src, dinv, N, E);
    convert_w_kernel<<<(IN_CH_K / 8 * CH + 255) / 256, 256, 0, stream>>>(W1, w1t, IN_CH_K);
    convert_w_kernel<<<(CH / 8 * CH + 255) / 256, 256, 0, stream>>>(W2, w2t, CH);

    const int gemm_grid = (N + 127) / 128;
    const int agg_grid = (N * 64 + 255) / 256;

    // ---- layer 1 ----
    gemm_mfma_kernel<IN_CH_K, false><<<gemm_grid, 256, 0, stream>>>(x, w1t, dinv, bufA, N);
    aggregate_kernel<<<agg_grid, 256, 0, stream>>>(bufA, row_off, csr_src, dinv, b1, out, N);

    // ---- layer 2 ----
    gemm_mfma_kernel<CH, true><<<gemm_grid, 256, 0, stream>>>(out, w2t, dinv, bufA, N);
    aggregate_kernel<<<agg_grid, 256, 0, stream>>>(bufA, row_off, csr_src, dinv, b2, out, N);
}

// Round 5
// 315.274 us; speedup vs baseline: 5.3218x; 1.3169x over previous
//
#include <hip/hip_runtime.h>
#include <hip/hip_bf16.h>

#define CH 128          // HID_CH == OUT_CH == 128
#define IN_CH_K 512
#define CHUNK 8192      // edges per bucket-sort block
#define BPAD 5120       // padded per-bucket capacity (expect ~4096, 16-sigma margin)

typedef short s16x8 __attribute__((ext_vector_type(8)));   // 8 bf16 (4 VGPRs)
typedef float f32x4 __attribute__((ext_vector_type(4)));

__device__ __forceinline__ unsigned int f2bf(float f) {
    unsigned int u = __builtin_bit_cast(unsigned int, f);
    return (u + 0x7fffu + ((u >> 16) & 1u)) >> 16;
}
__device__ __forceinline__ float bf_lo(unsigned int u) {
    return __builtin_bit_cast(float, u << 16);
}
__device__ __forceinline__ float bf_hi(unsigned int u) {
    return __builtin_bit_cast(float, u & 0xFFFF0000u);
}
// relu on 2 packed bf16: zero each 16-bit half whose sign bit is set
__device__ __forceinline__ unsigned int relu_pk(unsigned int w) {
    unsigned int keep = (~w) & 0x80008000u;      // 0x8000 where non-negative
    unsigned int mask = keep - (keep >> 15);     // 0x7FFF where non-negative, 0 where negative
    return w & mask;
}

// ---------------- bucket-sort CSR build ----------------
__global__ void init_cursor_kernel(int* __restrict__ cursor, int NB) {
    int i = blockIdx.x * blockDim.x + threadIdx.x;
    if (i < NB) cursor[i] = i * BPAD;
}

// bin edges into padded bucket regions; per-edge cursors in LDS, one global atomic per (block,bucket)
__global__ void bin_kernel(const int* __restrict__ src, const int* __restrict__ dst,
                           int* __restrict__ cursor, int* __restrict__ binned,
                           int E, int NB) {
    __shared__ int h[512];
    __shared__ int base[512];
    __shared__ int cur[512];
    for (int i = threadIdx.x; i < NB; i += 256) h[i] = 0;
    __syncthreads();
    const int beg = blockIdx.x * CHUNK;
    const int end = min(E, beg + CHUNK);
    for (int e = beg + threadIdx.x; e < end; e += 256)
        atomicAdd(&h[dst[e] >> 8], 1);
    __syncthreads();
    for (int i = threadIdx.x; i < NB; i += 256) {
        cur[i] = 0;
        if (h[i]) base[i] = atomicAdd(&cursor[i], h[i]);
    }
    __syncthreads();
    for (int e = beg + threadIdx.x; e < end; e += 256) {
        int d = dst[e];
        int b = d >> 8;
        int r = atomicAdd(&cur[b], 1);
        int idx = base[b] + r;
        if (idx < (b + 1) * BPAD)                    // defensive clamp (never expected)
            binned[idx] = src[e] | ((d & 255) << 17);   // src < 2^17
    }
}

// per-bucket (256 nodes) CSR finalize: row ranges, dinv, csr_src; per-edge atomics in LDS
__global__ void csr_bucket_kernel(const int* __restrict__ binned, const int* __restrict__ cursor,
                                  int2* __restrict__ row_range, int* __restrict__ csr_src,
                                  float* __restrict__ dinv, int N) {
    __shared__ int cnt[256];
    __shared__ int off[256];
    __shared__ int cur[256];
    const int k = blockIdx.x;
    const int t = threadIdx.x;
    cnt[t] = 0;
    __syncthreads();
    const int beg = k * BPAD;
    const int end = min(cursor[k], (k + 1) * BPAD);
    for (int e = beg + t; e < end; e += 256)
        atomicAdd(&cnt[binned[e] >> 17], 1);
    __syncthreads();
    int v = cnt[t];
    off[t] = v;
    __syncthreads();
    #pragma unroll
    for (int o = 1; o < 256; o <<= 1) {
        int tv = (t >= o) ? off[t - o] : 0;
        __syncthreads();
        off[t] += tv;
        __syncthreads();
    }
    int ex = off[t] - v;
    int node = k * 256 + t;
    if (node < N) {
        row_range[node] = make_int2(beg + ex, beg + ex + v);
        dinv[node] = rsqrtf((float)(v + 1));   // +1 self-loop
    }
    cur[t] = ex;
    __syncthreads();
    for (int e = beg + t; e < end; e += 256) {
        int p = binned[e];
        int dl = p >> 17;
        int r = atomicAdd(&cur[dl], 1);
        csr_src[beg + r] = p & 0x1FFFF;
    }
}

// ---------------- weight pre-transpose to MFMA B-fragment layout ----------------
// WT[g*128 + col] (uint4 = 8 bf16) holds W[k(g*8+j)][col], j=0..7.
// PERM: storage k' -> true k = (k'>>3) + ((k'&7)<<4)  (for layer 2, whose A cols are permuted)
template<bool PERM>
__global__ void convert_w_kernel(const float* __restrict__ W, uint4* __restrict__ WT, int K) {
    int i = blockIdx.x * blockDim.x + threadIdx.x;
    int ng = K >> 3;
    if (i >= ng * CH) return;
    int g = i >> 7;
    int col = i & 127;
    unsigned int h[8];
    #pragma unroll
    for (int j = 0; j < 8; ++j) {
        int kp = g * 8 + j;
        int k = PERM ? ((kp >> 3) + ((kp & 7) << 4)) : kp;
        h[j] = f2bf(W[(size_t)k * CH + col]);
    }
    uint4 v;
    v.x = h[0] | (h[1] << 16);
    v.y = h[2] | (h[3] << 16);
    v.z = h[4] | (h[5] << 16);
    v.w = h[6] | (h[7] << 16);
    WT[i] = v;
}

// ---------------- GEMM1: g1[M][128](bf16, permuted cols) = (x[M][512] @ W1) * dinv[row] ----------------
// storage col' = l15*8 + n  (true col = n*16 + l15)
__launch_bounds__(256)
__global__ void gemm1_mfma_kernel(const float* __restrict__ A, const uint4* __restrict__ WT,
                                  const float* __restrict__ dinv, unsigned short* __restrict__ C,
                                  int M) {
    const int tid = threadIdx.x;
    const int wid = tid >> 6;
    const int lane = tid & 63;
    const int l15 = lane & 15;
    const int lg = lane >> 4;

    const int block_row = blockIdx.x * 128 + wid * 32;

    f32x4 acc[2][8];
    #pragma unroll
    for (int m = 0; m < 2; ++m)
        #pragma unroll
        for (int n = 0; n < 8; ++n)
            acc[m][n] = (f32x4){0.f, 0.f, 0.f, 0.f};

    int arow0 = block_row + l15;
    int arow1 = block_row + 16 + l15;
    arow0 = (arow0 < M) ? arow0 : (M - 1);
    arow1 = (arow1 < M) ? arow1 : (M - 1);
    const float* aptr0 = A + (size_t)arow0 * IN_CH_K + lg * 8;
    const float* aptr1 = A + (size_t)arow1 * IN_CH_K + lg * 8;

    for (int k0 = 0; k0 < IN_CH_K; k0 += 32) {
        s16x8 afrag[2];
        #pragma unroll
        for (int m = 0; m < 2; ++m) {
            const float* ap = (m == 0 ? aptr0 : aptr1) + k0;
            float4 f0 = *reinterpret_cast<const float4*>(ap);
            float4 f1 = *reinterpret_cast<const float4*>(ap + 4);
            s16x8 a;
            a[0] = (short)f2bf(f0.x); a[1] = (short)f2bf(f0.y);
            a[2] = (short)f2bf(f0.z); a[3] = (short)f2bf(f0.w);
            a[4] = (short)f2bf(f1.x); a[5] = (short)f2bf(f1.y);
            a[6] = (short)f2bf(f1.z); a[7] = (short)f2bf(f1.w);
            afrag[m] = a;
        }
        const int gbase = (k0 >> 3) + lg;
        #pragma unroll
        for (int n = 0; n < 8; ++n) {
            uint4 bv = WT[(size_t)gbase * CH + n * 16 + l15];
            s16x8 b = __builtin_bit_cast(s16x8, bv);
            acc[0][n] = __builtin_amdgcn_mfma_f32_16x16x32_bf16(afrag[0], b, acc[0][n], 0, 0, 0);
            acc[1][n] = __builtin_amdgcn_mfma_f32_16x16x32_bf16(afrag[1], b, acc[1][n], 0, 0, 0);
        }
    }

    #pragma unroll
    for (int m = 0; m < 2; ++m) {
        #pragma unroll
        for (int i = 0; i < 4; ++i) {
            int row = block_row + m * 16 + lg * 4 + i;
            if (row < M) {
                float s = dinv[row];
                uint4 v;
                v.x = f2bf(acc[m][0][i] * s) | (f2bf(acc[m][1][i] * s) << 16);
                v.y = f2bf(acc[m][2][i] * s) | (f2bf(acc[m][3][i] * s) << 16);
                v.z = f2bf(acc[m][4][i] * s) | (f2bf(acc[m][5][i] * s) << 16);
                v.w = f2bf(acc[m][6][i] * s) | (f2bf(acc[m][7][i] * s) << 16);
                *reinterpret_cast<uint4*>(&C[(size_t)row * CH + l15 * 8]) = v;
            }
        }
    }
}

// ---------------- GEMM2: g2 = (relu(a1)[M][128] @ W2) * dinv[row], all bf16 permuted ----------------
// A is bf16 with permuted cols; WT2 pre-permuted to match; output same permuted layout.
__launch_bounds__(256)
__global__ void gemm2_mfma_kernel(const unsigned short* __restrict__ A, const uint4* __restrict__ WT,
                                  const float* __restrict__ dinv, unsigned short* __restrict__ C,
                                  int M) {
    const int tid = threadIdx.x;
    const int wid = tid >> 6;
    const int lane = tid & 63;
    const int l15 = lane & 15;
    const int lg = lane >> 4;

    const int block_row = blockIdx.x * 128 + wid * 32;

    f32x4 acc[2][8];
    #pragma unroll
    for (int m = 0; m < 2; ++m)
        #pragma unroll
        for (int n = 0; n < 8; ++n)
            acc[m][n] = (f32x4){0.f, 0.f, 0.f, 0.f};

    int arow0 = block_row + l15;
    int arow1 = block_row + 16 + l15;
    arow0 = (arow0 < M) ? arow0 : (M - 1);
    arow1 = (arow1 < M) ? arow1 : (M - 1);
    const uint4* ap0 = reinterpret_cast<const uint4*>(A + (size_t)arow0 * CH);
    const uint4* ap1 = reinterpret_cast<const uint4*>(A + (size_t)arow1 * CH);

    #pragma unroll
    for (int k0 = 0; k0 < CH; k0 += 32) {
        const int fi = (k0 >> 3) + lg;
        uint4 r0 = ap0[fi];
        uint4 r1 = ap1[fi];
        r0.x = relu_pk(r0.x); r0.y = relu_pk(r0.y); r0.z = relu_pk(r0.z); r0.w = relu_pk(r0.w);
        r1.x = relu_pk(r1.x); r1.y = relu_pk(r1.y); r1.z = relu_pk(r1.z); r1.w = relu_pk(r1.w);
        s16x8 a0 = __builtin_bit_cast(s16x8, r0);
        s16x8 a1 = __builtin_bit_cast(s16x8, r1);
        #pragma unroll
        for (int n = 0; n < 8; ++n) {
            uint4 bv = WT[(size_t)fi * CH + n * 16 + l15];
            s16x8 b = __builtin_bit_cast(s16x8, bv);
            acc[0][n] = __builtin_amdgcn_mfma_f32_16x16x32_bf16(a0, b, acc[0][n], 0, 0, 0);
            acc[1][n] = __builtin_amdgcn_mfma_f32_16x16x32_bf16(a1, b, acc[1][n], 0, 0, 0);
        }
    }

    #pragma unroll
    for (int m = 0; m < 2; ++m) {
        #pragma unroll
        for (int i = 0; i < 4; ++i) {
            int row = block_row + m * 16 + lg * 4 + i;
            if (row < M) {
                float s = dinv[row];
                uint4 v;
                v.x = f2bf(acc[m][0][i] * s) | (f2bf(acc[m][1][i] * s) << 16);
                v.y = f2bf(acc[m][2][i] * s) | (f2bf(acc[m][3][i] * s) << 16);
                v.z = f2bf(acc[m][4][i] * s) | (f2bf(acc[m][5][i] * s) << 16);
                v.w = f2bf(acc[m][6][i] * s) | (f2bf(acc[m][7][i] * s) << 16);
                *reinterpret_cast<uint4*>(&C[(size_t)row * CH + l15 * 8]) = v;
            }
        }
    }
}

// ---------------- aggregation: out[d] = dinv[d]*(g[d] + sum g[src]) + bias ----------------
// g is bf16 permuted-col [node][128]; one wave per node, 1 uint (2 bf16) per lane.
// OUT_BF16: write bf16 permuted (hidden layer). else: write f32 true-col order (d_out).
template<bool OUT_BF16>
__launch_bounds__(256)
__global__ void aggregate_kernel(const unsigned int* __restrict__ g, const int2* __restrict__ row_range,
                                 const int* __restrict__ csr_src, const float* __restrict__ dinv,
                                 const float* __restrict__ bias, void* __restrict__ outp, int N) {
    const int gtid = blockIdx.x * blockDim.x + threadIdx.x;
    const int node = gtid >> 6;
    if (node >= N) return;
    const int lane = threadIdx.x & 63;
    const int cp0 = lane << 1;                       // storage cols
    const int cp1 = cp0 | 1;
    const int c0 = (cp0 >> 3) + ((cp0 & 7) << 4);    // true cols
    const int c1 = (cp1 >> 3) + ((cp1 & 7) << 4);

    unsigned int su = g[(size_t)node * 64 + lane];   // self-loop term
    float ax = bf_lo(su);
    float ay = bf_hi(su);

    const int2 rr = row_range[node];
    int j = rr.x;
    const int end = rr.y;
    for (; j + 4 <= end; j += 4) {
        int s0 = __builtin_amdgcn_readfirstlane(csr_src[j]);
        int s1 = __builtin_amdgcn_readfirstlane(csr_src[j + 1]);
        int s2 = __builtin_amdgcn_readfirstlane(csr_src[j + 2]);
        int s3 = __builtin_amdgcn_readfirstlane(csr_src[j + 3]);
        unsigned int u0 = g[(size_t)s0 * 64 + lane];
        unsigned int u1 = g[(size_t)s1 * 64 + lane];
        unsigned int u2 = g[(size_t)s2 * 64 + lane];
        unsigned int u3 = g[(size_t)s3 * 64 + lane];
        ax += (bf_lo(u0) + bf_lo(u1)) + (bf_lo(u2) + bf_lo(u3));
        ay += (bf_hi(u0) + bf_hi(u1)) + (bf_hi(u2) + bf_hi(u3));
    }
    for (; j < end; ++j) {
        int s = __builtin_amdgcn_readfirstlane(csr_src[j]);
        unsigned int u = g[(size_t)s * 64 + lane];
        ax += bf_lo(u);
        ay += bf_hi(u);
    }

    const float di = dinv[node];
    float ox = di * ax + bias[c0];
    float oy = di * ay + bias[c1];
    if (OUT_BF16) {
        ((unsigned int*)outp)[(size_t)node * 64 + lane] = f2bf(ox) | (f2bf(oy) << 16);
    } else {
        float* o = (float*)outp + (size_t)node * CH;
        o[c0] = ox;
        o[c1] = oy;
    }
}

extern "C" void kernel_launch(void* const* d_in, const int* in_sizes, int n_in,
                              void* d_out, int out_size, void* d_ws, size_t ws_size,
                              hipStream_t stream) {
    const float* x  = (const float*)d_in[0];
    const int*   ei = (const int*)d_in[1];
    const float* W1 = (const float*)d_in[2];
    const float* b1 = (const float*)d_in[3];
    const float* W2 = (const float*)d_in[4];
    const float* b2 = (const float*)d_in[5];
    float* out = (float*)d_out;

    const int N = in_sizes[0] / IN_CH_K;       // 100000
    const int E = in_sizes[1] / 2;             // 1600000
    const int* e_src = ei;
    const int* e_dst = ei + E;

    const int NB = (N + 255) >> 8;             // 391 coarse buckets
    const int NCHUNK = (E + CHUNK - 1) / CHUNK;

    char* w = (char*)d_ws;
    auto alloc = [&](size_t bytes) {
        char* p = w;
        w += (bytes + 255) & ~(size_t)255;
        return p;
    };
    int*   cursor    = (int*)  alloc((size_t)NB * 4);
    int2*  row_range = (int2*) alloc((size_t)N * 8);
    float* dinv      = (float*)alloc((size_t)N * 4);
    int*   csr_src   = (int*)  alloc((size_t)NB * BPAD * 4);
    uint4* w1t       = (uint4*)alloc((size_t)(IN_CH_K / 8) * CH * 16);
    uint4* w2t       = (uint4*)alloc((size_t)(CH / 8) * CH * 16);
    unsigned short* gbuf = (unsigned short*)alloc((size_t)N * CH * 2);  // g1 / g2
    unsigned short* abuf = (unsigned short*)alloc((size_t)N * CH * 2);  // a1
    int* binned = (int*)gbuf;   // aliases gbuf (8 MB < 25.6 MB): dead before gemm1 writes

    // ---- CSR build (padded bucket sort) + weight conversion ----
    init_cursor_kernel<<<(NB + 255) / 256, 256, 0, stream>>>(cursor, NB);
    bin_kernel<<<NCHUNK, 256, 0, stream>>>(e_src, e_dst, cursor, binned, E, NB);
    csr_bucket_kernel<<<NB, 256, 0, stream>>>(binned, cursor, row_range, csr_src, dinv, N);
    convert_w_kernel<false><<<(IN_CH_K / 8 * CH + 255) / 256, 256, 0, stream>>>(W1, w1t, IN_CH_K);
    convert_w_kernel<true><<<(CH / 8 * CH + 255) / 256, 256, 0, stream>>>(W2, w2t, CH);

    const int gemm_grid = (N + 127) / 128;
    const int agg_grid = (N * 64 + 255) / 256;

    // ---- layer 1 ----
    gemm1_mfma_kernel<<<gemm_grid, 256, 0, stream>>>(x, w1t, dinv, gbuf, N);
    aggregate_kernel<true><<<agg_grid, 256, 0, stream>>>((const unsigned int*)gbuf, row_range,
                                                         csr_src, dinv, b1, abuf, N);

    // ---- layer 2 ----
    gemm2_mfma_kernel<<<gemm_grid, 256, 0, stream>>>(abuf, w2t, dinv, gbuf, N);
    aggregate_kernel<false><<<agg_grid, 256, 0, stream>>>((const unsigned int*)gbuf, row_range,
                                                          csr_src, dinv, b2, out, N);
}

// Round 6
// 288.958 us; speedup vs baseline: 5.8064x; 1.0911x over previous
//
#include <hip/hip_runtime.h>
#include <hip/hip_bf16.h>

#define CH 128          // HID_CH == OUT_CH == 128
#define IN_CH_K 512
#define CHUNK 2048      // edges per bucket-sort block (782 blocks -> ~3/CU)
#define BPAD 5120       // padded per-bucket capacity (expect ~4096, 16-sigma margin)

typedef short s16x8 __attribute__((ext_vector_type(8)));   // 8 bf16 (4 VGPRs)
typedef float f32x4 __attribute__((ext_vector_type(4)));

__device__ __forceinline__ unsigned int f2bf(float f) {
    unsigned int u = __builtin_bit_cast(unsigned int, f);
    return (u + 0x7fffu + ((u >> 16) & 1u)) >> 16;
}
// packed f32x2 -> bf16x2 via HW cvt (RNE, same bits as f2bf)
__device__ __forceinline__ unsigned int pk2bf(float lo, float hi) {
    unsigned int r;
    asm("v_cvt_pk_bf16_f32 %0, %1, %2" : "=v"(r) : "v"(lo), "v"(hi));
    return r;
}
__device__ __forceinline__ float bf_lo(unsigned int u) {
    return __builtin_bit_cast(float, u << 16);
}
__device__ __forceinline__ float bf_hi(unsigned int u) {
    return __builtin_bit_cast(float, u & 0xFFFF0000u);
}
// relu on 2 packed bf16: zero each 16-bit half whose sign bit is set
__device__ __forceinline__ unsigned int relu_pk(unsigned int w) {
    unsigned int keep = (~w) & 0x80008000u;
    unsigned int mask = keep - (keep >> 15);
    return w & mask;
}

// ---------------- bucket-sort CSR build ----------------
__global__ void init_cursor_kernel(int* __restrict__ cursor, int NB) {
    int i = blockIdx.x * blockDim.x + threadIdx.x;
    if (i < NB) cursor[i] = i * BPAD;
}

// bin edges into padded bucket regions; per-edge cursors in LDS, one global atomic per (block,bucket)
__global__ void bin_kernel(const int* __restrict__ src, const int* __restrict__ dst,
                           int* __restrict__ cursor, int* __restrict__ binned,
                           int E, int NB) {
    __shared__ int h[512];
    __shared__ int base[512];
    __shared__ int cur[512];
    const int tid = threadIdx.x;
    for (int i = tid; i < NB; i += 256) h[i] = 0;
    __syncthreads();

    const int E4 = E >> 2;
    const int beg4 = blockIdx.x * (CHUNK / 4);
    const int end4 = min(E4, beg4 + CHUNK / 4);
    const int4* dst4 = reinterpret_cast<const int4*>(dst);
    const int4* src4 = reinterpret_cast<const int4*>(src);
    const bool last = (blockIdx.x == gridDim.x - 1);

    for (int e4 = beg4 + tid; e4 < end4; e4 += 256) {
        int4 d = dst4[e4];
        atomicAdd(&h[d.x >> 8], 1);
        atomicAdd(&h[d.y >> 8], 1);
        atomicAdd(&h[d.z >> 8], 1);
        atomicAdd(&h[d.w >> 8], 1);
    }
    if (last) {
        for (int e = (E & ~3) + tid; e < E; e += 256)
            atomicAdd(&h[dst[e] >> 8], 1);
    }
    __syncthreads();
    for (int i = tid; i < NB; i += 256) {
        cur[i] = 0;
        if (h[i]) base[i] = atomicAdd(&cursor[i], h[i]);
    }
    __syncthreads();

    for (int e4 = beg4 + tid; e4 < end4; e4 += 256) {
        int4 d = dst4[e4];
        int4 s = src4[e4];
        int b, r, idx;
        b = d.x >> 8; r = atomicAdd(&cur[b], 1); idx = base[b] + r;
        if (idx < (b + 1) * BPAD) binned[idx] = s.x | ((d.x & 255) << 17);
        b = d.y >> 8; r = atomicAdd(&cur[b], 1); idx = base[b] + r;
        if (idx < (b + 1) * BPAD) binned[idx] = s.y | ((d.y & 255) << 17);
        b = d.z >> 8; r = atomicAdd(&cur[b], 1); idx = base[b] + r;
        if (idx < (b + 1) * BPAD) binned[idx] = s.z | ((d.z & 255) << 17);
        b = d.w >> 8; r = atomicAdd(&cur[b], 1); idx = base[b] + r;
        if (idx < (b + 1) * BPAD) binned[idx] = s.w | ((d.w & 255) << 17);
    }
    if (last) {
        for (int e = (E & ~3) + tid; e < E; e += 256) {
            int d = dst[e];
            int b = d >> 8;
            int r = atomicAdd(&cur[b], 1);
            int idx = base[b] + r;
            if (idx < (b + 1) * BPAD) binned[idx] = src[e] | ((d & 255) << 17);
        }
    }
}

// per-bucket (256 nodes) CSR finalize: row ranges, dinv, csr_src; per-edge atomics in LDS
__global__ void csr_bucket_kernel(const int* __restrict__ binned, const int* __restrict__ cursor,
                                  int2* __restrict__ row_range, int* __restrict__ csr_src,
                                  float* __restrict__ dinv, int N) {
    __shared__ int cnt[256];
    __shared__ int off[256];
    __shared__ int cur[256];
    const int k = blockIdx.x;
    const int t = threadIdx.x;
    cnt[t] = 0;
    __syncthreads();
    const int beg = k * BPAD;
    const int end = min(cursor[k], (k + 1) * BPAD);
    const int nv = (end - beg) & ~3;        // vectorizable count (beg is 16B-aligned)
    const int4* b4 = reinterpret_cast<const int4*>(binned + beg);

    for (int q = t; q * 4 < nv; q += 256) {
        int4 p = b4[q];
        atomicAdd(&cnt[p.x >> 17], 1);
        atomicAdd(&cnt[p.y >> 17], 1);
        atomicAdd(&cnt[p.z >> 17], 1);
        atomicAdd(&cnt[p.w >> 17], 1);
    }
    for (int e = beg + nv + t; e < end; e += 256)
        atomicAdd(&cnt[binned[e] >> 17], 1);
    __syncthreads();
    int v = cnt[t];
    off[t] = v;
    __syncthreads();
    #pragma unroll
    for (int o = 1; o < 256; o <<= 1) {
        int tv = (t >= o) ? off[t - o] : 0;
        __syncthreads();
        off[t] += tv;
        __syncthreads();
    }
    int ex = off[t] - v;
    int node = k * 256 + t;
    if (node < N) {
        row_range[node] = make_int2(beg + ex, beg + ex + v);
        dinv[node] = rsqrtf((float)(v + 1));   // +1 self-loop
    }
    cur[t] = ex;
    __syncthreads();
    for (int q = t; q * 4 < nv; q += 256) {
        int4 p = b4[q];
        int dl, r;
        dl = p.x >> 17; r = atomicAdd(&cur[dl], 1); csr_src[beg + r] = p.x & 0x1FFFF;
        dl = p.y >> 17; r = atomicAdd(&cur[dl], 1); csr_src[beg + r] = p.y & 0x1FFFF;
        dl = p.z >> 17; r = atomicAdd(&cur[dl], 1); csr_src[beg + r] = p.z & 0x1FFFF;
        dl = p.w >> 17; r = atomicAdd(&cur[dl], 1); csr_src[beg + r] = p.w & 0x1FFFF;
    }
    for (int e = beg + nv + t; e < end; e += 256) {
        int p = binned[e];
        int dl = p >> 17;
        int r = atomicAdd(&cur[dl], 1);
        csr_src[beg + r] = p & 0x1FFFF;
    }
}

// ---------------- weight pre-transpose to MFMA B-fragment layout ----------------
// WT[g*128 + col] (uint4 = 8 bf16) holds W[k(g*8+j)][col], j=0..7.
// PERM: storage k' -> true k = (k'>>3) + ((k'&7)<<4)  (layer 2: A cols are permuted)
template<bool PERM>
__global__ void convert_w_kernel(const float* __restrict__ W, uint4* __restrict__ WT, int K) {
    int i = blockIdx.x * blockDim.x + threadIdx.x;
    int ng = K >> 3;
    if (i >= ng * CH) return;
    int g = i >> 7;
    int col = i & 127;
    unsigned int h[8];
    #pragma unroll
    for (int j = 0; j < 8; ++j) {
        int kp = g * 8 + j;
        int k = PERM ? ((kp >> 3) + ((kp & 7) << 4)) : kp;
        h[j] = f2bf(W[(size_t)k * CH + col]);
    }
    uint4 v;
    v.x = h[0] | (h[1] << 16);
    v.y = h[2] | (h[3] << 16);
    v.z = h[4] | (h[5] << 16);
    v.w = h[6] | (h[7] << 16);
    WT[i] = v;
}

// ---------------- GEMM1: g1[M][128](bf16, permuted cols) = (x[M][512] @ W1) * dinv[row] ----------------
// storage col' = l15*8 + n  (true col = n*16 + l15)
__launch_bounds__(256)
__global__ void gemm1_mfma_kernel(const float* __restrict__ A, const uint4* __restrict__ WT,
                                  const float* __restrict__ dinv, unsigned short* __restrict__ C,
                                  int M) {
    const int tid = threadIdx.x;
    const int wid = tid >> 6;
    const int lane = tid & 63;
    const int l15 = lane & 15;
    const int lg = lane >> 4;

    const int block_row = blockIdx.x * 128 + wid * 32;

    f32x4 acc[2][8];
    #pragma unroll
    for (int m = 0; m < 2; ++m)
        #pragma unroll
        for (int n = 0; n < 8; ++n)
            acc[m][n] = (f32x4){0.f, 0.f, 0.f, 0.f};

    int arow0 = block_row + l15;
    int arow1 = block_row + 16 + l15;
    arow0 = (arow0 < M) ? arow0 : (M - 1);
    arow1 = (arow1 < M) ? arow1 : (M - 1);
    const float* aptr0 = A + (size_t)arow0 * IN_CH_K + lg * 8;
    const float* aptr1 = A + (size_t)arow1 * IN_CH_K + lg * 8;

    #pragma unroll 2
    for (int k0 = 0; k0 < IN_CH_K; k0 += 32) {
        s16x8 afrag[2];
        #pragma unroll
        for (int m = 0; m < 2; ++m) {
            const float* ap = (m == 0 ? aptr0 : aptr1) + k0;
            float4 f0 = *reinterpret_cast<const float4*>(ap);
            float4 f1 = *reinterpret_cast<const float4*>(ap + 4);
            uint4 pk;
            pk.x = pk2bf(f0.x, f0.y);
            pk.y = pk2bf(f0.z, f0.w);
            pk.z = pk2bf(f1.x, f1.y);
            pk.w = pk2bf(f1.z, f1.w);
            afrag[m] = __builtin_bit_cast(s16x8, pk);
        }
        const int gbase = (k0 >> 3) + lg;
        #pragma unroll
        for (int n = 0; n < 8; ++n) {
            uint4 bv = WT[(size_t)gbase * CH + n * 16 + l15];
            s16x8 b = __builtin_bit_cast(s16x8, bv);
            acc[0][n] = __builtin_amdgcn_mfma_f32_16x16x32_bf16(afrag[0], b, acc[0][n], 0, 0, 0);
            acc[1][n] = __builtin_amdgcn_mfma_f32_16x16x32_bf16(afrag[1], b, acc[1][n], 0, 0, 0);
        }
    }

    #pragma unroll
    for (int m = 0; m < 2; ++m) {
        #pragma unroll
        for (int i = 0; i < 4; ++i) {
            int row = block_row + m * 16 + lg * 4 + i;
            if (row < M) {
                float s = dinv[row];
                uint4 v;
                v.x = pk2bf(acc[m][0][i] * s, acc[m][1][i] * s);
                v.y = pk2bf(acc[m][2][i] * s, acc[m][3][i] * s);
                v.z = pk2bf(acc[m][4][i] * s, acc[m][5][i] * s);
                v.w = pk2bf(acc[m][6][i] * s, acc[m][7][i] * s);
                *reinterpret_cast<uint4*>(&C[(size_t)row * CH + l15 * 8]) = v;
            }
        }
    }
}

// ---------------- GEMM2: g2 = (relu(a1)[M][128] @ W2) * dinv[row], all bf16 permuted ----------------
__launch_bounds__(256)
__global__ void gemm2_mfma_kernel(const unsigned short* __restrict__ A, const uint4* __restrict__ WT,
                                  const float* __restrict__ dinv, unsigned short* __restrict__ C,
                                  int M) {
    const int tid = threadIdx.x;
    const int wid = tid >> 6;
    const int lane = tid & 63;
    const int l15 = lane & 15;
    const int lg = lane >> 4;

    const int block_row = blockIdx.x * 128 + wid * 32;

    f32x4 acc[2][8];
    #pragma unroll
    for (int m = 0; m < 2; ++m)
        #pragma unroll
        for (int n = 0; n < 8; ++n)
            acc[m][n] = (f32x4){0.f, 0.f, 0.f, 0.f};

    int arow0 = block_row + l15;
    int arow1 = block_row + 16 + l15;
    arow0 = (arow0 < M) ? arow0 : (M - 1);
    arow1 = (arow1 < M) ? arow1 : (M - 1);
    const uint4* ap0 = reinterpret_cast<const uint4*>(A + (size_t)arow0 * CH);
    const uint4* ap1 = reinterpret_cast<const uint4*>(A + (size_t)arow1 * CH);

    #pragma unroll
    for (int k0 = 0; k0 < CH; k0 += 32) {
        const int fi = (k0 >> 3) + lg;
        uint4 r0 = ap0[fi];
        uint4 r1 = ap1[fi];
        r0.x = relu_pk(r0.x); r0.y = relu_pk(r0.y); r0.z = relu_pk(r0.z); r0.w = relu_pk(r0.w);
        r1.x = relu_pk(r1.x); r1.y = relu_pk(r1.y); r1.z = relu_pk(r1.z); r1.w = relu_pk(r1.w);
        s16x8 a0 = __builtin_bit_cast(s16x8, r0);
        s16x8 a1 = __builtin_bit_cast(s16x8, r1);
        #pragma unroll
        for (int n = 0; n < 8; ++n) {
            uint4 bv = WT[(size_t)fi * CH + n * 16 + l15];
            s16x8 b = __builtin_bit_cast(s16x8, bv);
            acc[0][n] = __builtin_amdgcn_mfma_f32_16x16x32_bf16(a0, b, acc[0][n], 0, 0, 0);
            acc[1][n] = __builtin_amdgcn_mfma_f32_16x16x32_bf16(a1, b, acc[1][n], 0, 0, 0);
        }
    }

    #pragma unroll
    for (int m = 0; m < 2; ++m) {
        #pragma unroll
        for (int i = 0; i < 4; ++i) {
            int row = block_row + m * 16 + lg * 4 + i;
            if (row < M) {
                float s = dinv[row];
                uint4 v;
                v.x = pk2bf(acc[m][0][i] * s, acc[m][1][i] * s);
                v.y = pk2bf(acc[m][2][i] * s, acc[m][3][i] * s);
                v.z = pk2bf(acc[m][4][i] * s, acc[m][5][i] * s);
                v.w = pk2bf(acc[m][6][i] * s, acc[m][7][i] * s);
                *reinterpret_cast<uint4*>(&C[(size_t)row * CH + l15 * 8]) = v;
            }
        }
    }
}

// ---------------- aggregation: out[d] = dinv[d]*(g[d] + sum g[src]) + bias ----------------
// g is bf16 permuted-col [node][128]; one wave per node, 1 uint (2 bf16) per lane.
// 8-deep software-pipelined gather: next batch's indices load while current gathers fly.
#define GATHER(cc) g[(size_t)__builtin_amdgcn_readfirstlane(cc) * 64 + lane]
template<bool OUT_BF16>
__launch_bounds__(256)
__global__ void aggregate_kernel(const unsigned int* __restrict__ g, const int2* __restrict__ row_range,
                                 const int* __restrict__ csr_src, const float* __restrict__ dinv,
                                 const float* __restrict__ bias, void* __restrict__ outp, int N) {
    const int gtid = blockIdx.x * blockDim.x + threadIdx.x;
    const int node = gtid >> 6;
    if (node >= N) return;
    const int lane = threadIdx.x & 63;

    unsigned int su = g[(size_t)node * 64 + lane];   // self-loop term
    const int2 rr = row_range[node];
    float ax = bf_lo(su);
    float ay = bf_hi(su);

    int j = rr.x;
    const int end = rr.y;

    if (j + 8 <= end) {
        int c0 = csr_src[j], c1 = csr_src[j+1], c2 = csr_src[j+2], c3 = csr_src[j+3];
        int c4 = csr_src[j+4], c5 = csr_src[j+5], c6 = csr_src[j+6], c7 = csr_src[j+7];
        j += 8;
        while (j + 8 <= end) {
            int n0 = csr_src[j], n1 = csr_src[j+1], n2 = csr_src[j+2], n3 = csr_src[j+3];
            int n4 = csr_src[j+4], n5 = csr_src[j+5], n6 = csr_src[j+6], n7 = csr_src[j+7];
            j += 8;
            unsigned int u0 = GATHER(c0), u1 = GATHER(c1), u2 = GATHER(c2), u3 = GATHER(c3);
            unsigned int u4 = GATHER(c4), u5 = GATHER(c5), u6 = GATHER(c6), u7 = GATHER(c7);
            ax += ((bf_lo(u0) + bf_lo(u1)) + (bf_lo(u2) + bf_lo(u3)))
                + ((bf_lo(u4) + bf_lo(u5)) + (bf_lo(u6) + bf_lo(u7)));
            ay += ((bf_hi(u0) + bf_hi(u1)) + (bf_hi(u2) + bf_hi(u3)))
                + ((bf_hi(u4) + bf_hi(u5)) + (bf_hi(u6) + bf_hi(u7)));
            c0 = n0; c1 = n1; c2 = n2; c3 = n3;
            c4 = n4; c5 = n5; c6 = n6; c7 = n7;
        }
        unsigned int u0 = GATHER(c0), u1 = GATHER(c1), u2 = GATHER(c2), u3 = GATHER(c3);
        unsigned int u4 = GATHER(c4), u5 = GATHER(c5), u6 = GATHER(c6), u7 = GATHER(c7);
        ax += ((bf_lo(u0) + bf_lo(u1)) + (bf_lo(u2) + bf_lo(u3)))
            + ((bf_lo(u4) + bf_lo(u5)) + (bf_lo(u6) + bf_lo(u7)));
        ay += ((bf_hi(u0) + bf_hi(u1)) + (bf_hi(u2) + bf_hi(u3)))
            + ((bf_hi(u4) + bf_hi(u5)) + (bf_hi(u6) + bf_hi(u7)));
    }
    for (; j + 2 <= end; j += 2) {
        int c0 = csr_src[j], c1 = csr_src[j+1];
        unsigned int u0 = GATHER(c0), u1 = GATHER(c1);
        ax += bf_lo(u0) + bf_lo(u1);
        ay += bf_hi(u0) + bf_hi(u1);
    }
    if (j < end) {
        int c0 = csr_src[j];
        unsigned int u0 = GATHER(c0);
        ax += bf_lo(u0);
        ay += bf_hi(u0);
    }

    const int cp0 = lane << 1;
    const int cp1 = cp0 | 1;
    const int c0 = (cp0 >> 3) + ((cp0 & 7) << 4);    // true cols
    const int c1 = (cp1 >> 3) + ((cp1 & 7) << 4);
    const float di = dinv[node];
    float ox = di * ax + bias[c0];
    float oy = di * ay + bias[c1];
    if (OUT_BF16) {
        ((unsigned int*)outp)[(size_t)node * 64 + lane] = pk2bf(ox, oy);
    } else {
        float* o = (float*)outp + (size_t)node * CH;
        o[c0] = ox;
        o[c1] = oy;
    }
}

extern "C" void kernel_launch(void* const* d_in, const int* in_sizes, int n_in,
                              void* d_out, int out_size, void* d_ws, size_t ws_size,
                              hipStream_t stream) {
    const float* x  = (const float*)d_in[0];
    const int*   ei = (const int*)d_in[1];
    const float* W1 = (const float*)d_in[2];
    const float* b1 = (const float*)d_in[3];
    const float* W2 = (const float*)d_in[4];
    const float* b2 = (const float*)d_in[5];
    float* out = (float*)d_out;

    const int N = in_sizes[0] / IN_CH_K;       // 100000
    const int E = in_sizes[1] / 2;             // 1600000
    const int* e_src = ei;
    const int* e_dst = ei + E;

    const int NB = (N + 255) >> 8;             // 391 coarse buckets
    const int NCHUNK = (E + CHUNK - 1) / CHUNK;

    char* w = (char*)d_ws;
    auto alloc = [&](size_t bytes) {
        char* p = w;
        w += (bytes + 255) & ~(size_t)255;
        return p;
    };
    int*   cursor    = (int*)  alloc((size_t)NB * 4);
    int2*  row_range = (int2*) alloc((size_t)N * 8);
    float* dinv      = (float*)alloc((size_t)N * 4);
    int*   csr_src   = (int*)  alloc((size_t)NB * BPAD * 4);
    uint4* w1t       = (uint4*)alloc((size_t)(IN_CH_K / 8) * CH * 16);
    uint4* w2t       = (uint4*)alloc((size_t)(CH / 8) * CH * 16);
    unsigned short* gbuf = (unsigned short*)alloc((size_t)N * CH * 2);  // g1 / g2
    unsigned short* abuf = (unsigned short*)alloc((size_t)N * CH * 2);  // a1
    int* binned = (int*)gbuf;   // aliases gbuf (8 MB < 25.6 MB): dead before gemm1 writes

    // ---- CSR build (padded bucket sort) + weight conversion ----
    init_cursor_kernel<<<(NB + 255) / 256, 256, 0, stream>>>(cursor, NB);
    bin_kernel<<<NCHUNK, 256, 0, stream>>>(e_src, e_dst, cursor, binned, E, NB);
    csr_bucket_kernel<<<NB, 256, 0, stream>>>(binned, cursor, row_range, csr_src, dinv, N);
    convert_w_kernel<false><<<(IN_CH_K / 8 * CH + 255) / 256, 256, 0, stream>>>(W1, w1t, IN_CH_K);
    convert_w_kernel<true><<<(CH / 8 * CH + 255) / 256, 256, 0, stream>>>(W2, w2t, CH);

    const int gemm_grid = (N + 127) / 128;
    const int agg_grid = (N * 64 + 255) / 256;

    // ---- layer 1 ----
    gemm1_mfma_kernel<<<gemm_grid, 256, 0, stream>>>(x, w1t, dinv, gbuf, N);
    aggregate_kernel<true><<<agg_grid, 256, 0, stream>>>((const unsigned int*)gbuf, row_range,
                                                         csr_src, dinv, b1, abuf, N);

    // ---- layer 2 ----
    gemm2_mfma_kernel<<<gemm_grid, 256, 0, stream>>>(abuf, w2t, dinv, gbuf, N);
    aggregate_kernel<false><<<agg_grid, 256, 0, stream>>>((const unsigned int*)gbuf, row_range,
                                                          csr_src, dinv, b2, out, N);
}

// Round 7
// 276.711 us; speedup vs baseline: 6.0634x; 1.0443x over previous
//
#include <hip/hip_runtime.h>
#include <hip/hip_bf16.h>

#define CH 128          // HID_CH == OUT_CH == 128
#define IN_CH_K 512
#define CHUNK 2048      // edges per bucket-sort block (782 blocks -> ~3/CU)
#define BPAD 5120       // padded per-bucket capacity (expect ~4096, 16-sigma margin)

typedef short s16x8 __attribute__((ext_vector_type(8)));   // 8 bf16 (4 VGPRs)
typedef float f32x4 __attribute__((ext_vector_type(4)));

__device__ __forceinline__ unsigned int f2bf(float f) {
    unsigned int u = __builtin_bit_cast(unsigned int, f);
    return (u + 0x7fffu + ((u >> 16) & 1u)) >> 16;
}
// packed f32x2 -> bf16x2 via HW cvt (RNE, same bits as f2bf)
__device__ __forceinline__ unsigned int pk2bf(float lo, float hi) {
    unsigned int r;
    asm("v_cvt_pk_bf16_f32 %0, %1, %2" : "=v"(r) : "v"(lo), "v"(hi));
    return r;
}
__device__ __forceinline__ float bf_lo(unsigned int u) {
    return __builtin_bit_cast(float, u << 16);
}
__device__ __forceinline__ float bf_hi(unsigned int u) {
    return __builtin_bit_cast(float, u & 0xFFFF0000u);
}
// relu on 2 packed bf16: zero each 16-bit half whose sign bit is set
__device__ __forceinline__ unsigned int relu_pk(unsigned int w) {
    unsigned int keep = (~w) & 0x80008000u;
    unsigned int mask = keep - (keep >> 15);
    return w & mask;
}

// ---------------- bucket-sort CSR build ----------------
__global__ void init_cursor_kernel(int* __restrict__ cursor, int NB) {
    int i = blockIdx.x * blockDim.x + threadIdx.x;
    if (i < NB) cursor[i] = i * BPAD;
}

// bin edges into padded bucket regions; per-edge cursors in LDS, one global atomic per (block,bucket)
__global__ void bin_kernel(const int* __restrict__ src, const int* __restrict__ dst,
                           int* __restrict__ cursor, int* __restrict__ binned,
                           int E, int NB) {
    __shared__ int h[512];
    __shared__ int base[512];
    __shared__ int cur[512];
    const int tid = threadIdx.x;
    for (int i = tid; i < NB; i += 256) h[i] = 0;
    __syncthreads();

    const int E4 = E >> 2;
    const int beg4 = blockIdx.x * (CHUNK / 4);
    const int end4 = min(E4, beg4 + CHUNK / 4);
    const int4* dst4 = reinterpret_cast<const int4*>(dst);
    const int4* src4 = reinterpret_cast<const int4*>(src);
    const bool last = (blockIdx.x == gridDim.x - 1);

    for (int e4 = beg4 + tid; e4 < end4; e4 += 256) {
        int4 d = dst4[e4];
        atomicAdd(&h[d.x >> 8], 1);
        atomicAdd(&h[d.y >> 8], 1);
        atomicAdd(&h[d.z >> 8], 1);
        atomicAdd(&h[d.w >> 8], 1);
    }
    if (last) {
        for (int e = (E & ~3) + tid; e < E; e += 256)
            atomicAdd(&h[dst[e] >> 8], 1);
    }
    __syncthreads();
    for (int i = tid; i < NB; i += 256) {
        cur[i] = 0;
        if (h[i]) base[i] = atomicAdd(&cursor[i], h[i]);
    }
    __syncthreads();

    for (int e4 = beg4 + tid; e4 < end4; e4 += 256) {
        int4 d = dst4[e4];
        int4 s = src4[e4];
        int b, r, idx;
        b = d.x >> 8; r = atomicAdd(&cur[b], 1); idx = base[b] + r;
        if (idx < (b + 1) * BPAD) binned[idx] = s.x | ((d.x & 255) << 17);
        b = d.y >> 8; r = atomicAdd(&cur[b], 1); idx = base[b] + r;
        if (idx < (b + 1) * BPAD) binned[idx] = s.y | ((d.y & 255) << 17);
        b = d.z >> 8; r = atomicAdd(&cur[b], 1); idx = base[b] + r;
        if (idx < (b + 1) * BPAD) binned[idx] = s.z | ((d.z & 255) << 17);
        b = d.w >> 8; r = atomicAdd(&cur[b], 1); idx = base[b] + r;
        if (idx < (b + 1) * BPAD) binned[idx] = s.w | ((d.w & 255) << 17);
    }
    if (last) {
        for (int e = (E & ~3) + tid; e < E; e += 256) {
            int d = dst[e];
            int b = d >> 8;
            int r = atomicAdd(&cur[b], 1);
            int idx = base[b] + r;
            if (idx < (b + 1) * BPAD) binned[idx] = src[e] | ((d & 255) << 17);
        }
    }
}

// per-bucket (256 nodes) CSR finalize: row ranges, dinv, csr_src; per-edge atomics in LDS
__global__ void csr_bucket_kernel(const int* __restrict__ binned, const int* __restrict__ cursor,
                                  int2* __restrict__ row_range, int* __restrict__ csr_src,
                                  float* __restrict__ dinv, int N) {
    __shared__ int cnt[256];
    __shared__ int off[256];
    __shared__ int cur[256];
    const int k = blockIdx.x;
    const int t = threadIdx.x;
    cnt[t] = 0;
    __syncthreads();
    const int beg = k * BPAD;
    const int end = min(cursor[k], (k + 1) * BPAD);
    const int nv = (end - beg) & ~3;        // vectorizable count (beg is 16B-aligned)
    const int4* b4 = reinterpret_cast<const int4*>(binned + beg);

    for (int q = t; q * 4 < nv; q += 256) {
        int4 p = b4[q];
        atomicAdd(&cnt[p.x >> 17], 1);
        atomicAdd(&cnt[p.y >> 17], 1);
        atomicAdd(&cnt[p.z >> 17], 1);
        atomicAdd(&cnt[p.w >> 17], 1);
    }
    for (int e = beg + nv + t; e < end; e += 256)
        atomicAdd(&cnt[binned[e] >> 17], 1);
    __syncthreads();
    int v = cnt[t];
    off[t] = v;
    __syncthreads();
    #pragma unroll
    for (int o = 1; o < 256; o <<= 1) {
        int tv = (t >= o) ? off[t - o] : 0;
        __syncthreads();
        off[t] += tv;
        __syncthreads();
    }
    int ex = off[t] - v;
    int node = k * 256 + t;
    if (node < N) {
        row_range[node] = make_int2(beg + ex, beg + ex + v);
        dinv[node] = rsqrtf((float)(v + 1));   // +1 self-loop
    }
    cur[t] = ex;
    __syncthreads();
    for (int q = t; q * 4 < nv; q += 256) {
        int4 p = b4[q];
        int dl, r;
        dl = p.x >> 17; r = atomicAdd(&cur[dl], 1); csr_src[beg + r] = p.x & 0x1FFFF;
        dl = p.y >> 17; r = atomicAdd(&cur[dl], 1); csr_src[beg + r] = p.y & 0x1FFFF;
        dl = p.z >> 17; r = atomicAdd(&cur[dl], 1); csr_src[beg + r] = p.z & 0x1FFFF;
        dl = p.w >> 17; r = atomicAdd(&cur[dl], 1); csr_src[beg + r] = p.w & 0x1FFFF;
    }
    for (int e = beg + nv + t; e < end; e += 256) {
        int p = binned[e];
        int dl = p >> 17;
        int r = atomicAdd(&cur[dl], 1);
        csr_src[beg + r] = p & 0x1FFFF;
    }
}

// ---------------- weight pre-transpose to MFMA B-fragment layout ----------------
// WT[g*128 + col] (uint4 = 8 bf16) holds W[k(g*8+j)][col], j=0..7.
// PERM: storage k' -> true k = (k'>>3) + ((k'&7)<<4)  (layer 2: A cols are permuted)
template<bool PERM>
__global__ void convert_w_kernel(const float* __restrict__ W, uint4* __restrict__ WT, int K) {
    int i = blockIdx.x * blockDim.x + threadIdx.x;
    int ng = K >> 3;
    if (i >= ng * CH) return;
    int g = i >> 7;
    int col = i & 127;
    unsigned int h[8];
    #pragma unroll
    for (int j = 0; j < 8; ++j) {
        int kp = g * 8 + j;
        int k = PERM ? ((kp >> 3) + ((kp & 7) << 4)) : kp;
        h[j] = f2bf(W[(size_t)k * CH + col]);
    }
    uint4 v;
    v.x = h[0] | (h[1] << 16);
    v.y = h[2] | (h[3] << 16);
    v.z = h[4] | (h[5] << 16);
    v.w = h[6] | (h[7] << 16);
    WT[i] = v;
}

// ---------------- GEMM1: g1[M][128](bf16, permuted cols) = (x[M][512] @ W1) * dinv[row] ----------------
// Explicit 1-deep register double-buffer pipeline, fully unrolled over 16 k-steps:
// next k-step's A rows (HBM/L3) and B fragments (L1/L2) load while current k-step MFMAs.
// storage col' = l15*8 + n  (true col = n*16 + l15)
__launch_bounds__(256)
__global__ void gemm1_mfma_kernel(const float* __restrict__ A, const uint4* __restrict__ WT,
                                  const float* __restrict__ dinv, unsigned short* __restrict__ C,
                                  int M) {
    const int tid = threadIdx.x;
    const int wid = tid >> 6;
    const int lane = tid & 63;
    const int l15 = lane & 15;
    const int lg = lane >> 4;

    const int block_row = blockIdx.x * 128 + wid * 32;

    f32x4 acc[2][8];
    #pragma unroll
    for (int m = 0; m < 2; ++m)
        #pragma unroll
        for (int n = 0; n < 8; ++n)
            acc[m][n] = (f32x4){0.f, 0.f, 0.f, 0.f};

    const int arow0 = min(block_row + l15, M - 1);
    const int arow1 = min(block_row + 16 + l15, M - 1);
    // float4-typed row pointers at this lane's k-subslice (lg*8 floats = 2 float4)
    const float4* ap0 = reinterpret_cast<const float4*>(A + (size_t)arow0 * IN_CH_K) + lg * 2;
    const float4* ap1 = reinterpret_cast<const float4*>(A + (size_t)arow1 * IN_CH_K) + lg * 2;
    const uint4* wp = WT + (size_t)lg * CH + l15;   // advance by 4*CH per k-step; +16*n per frag

    // ---- prologue: load k-step 0 ----
    float4 a00 = ap0[0], a01 = ap0[1];
    float4 a10 = ap1[0], a11 = ap1[1];
    uint4 bw[8];
    #pragma unroll
    for (int n = 0; n < 8; ++n) bw[n] = wp[n * 16];

    #pragma unroll
    for (int ks = 0; ks < 16; ++ks) {
        // ---- issue next k-step's loads (A first: longest latency) ----
        float4 na00, na01, na10, na11;
        uint4 nbw[8];
        if (ks < 15) {
            const int o4 = (ks + 1) * 8;           // 32 floats = 8 float4 per k-step
            na00 = ap0[o4];     na01 = ap0[o4 + 1];
            na10 = ap1[o4];     na11 = ap1[o4 + 1];
            const uint4* nwp = wp + (size_t)(ks + 1) * 4 * CH;
            #pragma unroll
            for (int n = 0; n < 8; ++n) nbw[n] = nwp[n * 16];
        }

        // ---- convert current A to bf16 fragments ----
        uint4 pk0, pk1;
        pk0.x = pk2bf(a00.x, a00.y);  pk0.y = pk2bf(a00.z, a00.w);
        pk0.z = pk2bf(a01.x, a01.y);  pk0.w = pk2bf(a01.z, a01.w);
        pk1.x = pk2bf(a10.x, a10.y);  pk1.y = pk2bf(a10.z, a10.w);
        pk1.z = pk2bf(a11.x, a11.y);  pk1.w = pk2bf(a11.z, a11.w);
        s16x8 af0 = __builtin_bit_cast(s16x8, pk0);
        s16x8 af1 = __builtin_bit_cast(s16x8, pk1);

        // ---- MFMA on current buffers ----
        #pragma unroll
        for (int n = 0; n < 8; ++n) {
            s16x8 b = __builtin_bit_cast(s16x8, bw[n]);
            acc[0][n] = __builtin_amdgcn_mfma_f32_16x16x32_bf16(af0, b, acc[0][n], 0, 0, 0);
            acc[1][n] = __builtin_amdgcn_mfma_f32_16x16x32_bf16(af1, b, acc[1][n], 0, 0, 0);
        }

        // ---- rotate (statically renamed by full unroll) ----
        if (ks < 15) {
            a00 = na00; a01 = na01; a10 = na10; a11 = na11;
            #pragma unroll
            for (int n = 0; n < 8; ++n) bw[n] = nbw[n];
        }
    }

    #pragma unroll
    for (int m = 0; m < 2; ++m) {
        #pragma unroll
        for (int i = 0; i < 4; ++i) {
            int row = block_row + m * 16 + lg * 4 + i;
            if (row < M) {
                float s = dinv[row];
                uint4 v;
                v.x = pk2bf(acc[m][0][i] * s, acc[m][1][i] * s);
                v.y = pk2bf(acc[m][2][i] * s, acc[m][3][i] * s);
                v.z = pk2bf(acc[m][4][i] * s, acc[m][5][i] * s);
                v.w = pk2bf(acc[m][6][i] * s, acc[m][7][i] * s);
                *reinterpret_cast<uint4*>(&C[(size_t)row * CH + l15 * 8]) = v;
            }
        }
    }
}

// ---------------- GEMM2: g2 = (relu(a1)[M][128] @ W2) * dinv[row], all bf16 permuted ----------------
__launch_bounds__(256)
__global__ void gemm2_mfma_kernel(const unsigned short* __restrict__ A, const uint4* __restrict__ WT,
                                  const float* __restrict__ dinv, unsigned short* __restrict__ C,
                                  int M) {
    const int tid = threadIdx.x;
    const int wid = tid >> 6;
    const int lane = tid & 63;
    const int l15 = lane & 15;
    const int lg = lane >> 4;

    const int block_row = blockIdx.x * 128 + wid * 32;

    f32x4 acc[2][8];
    #pragma unroll
    for (int m = 0; m < 2; ++m)
        #pragma unroll
        for (int n = 0; n < 8; ++n)
            acc[m][n] = (f32x4){0.f, 0.f, 0.f, 0.f};

    int arow0 = min(block_row + l15, M - 1);
    int arow1 = min(block_row + 16 + l15, M - 1);
    const uint4* ap0 = reinterpret_cast<const uint4*>(A + (size_t)arow0 * CH);
    const uint4* ap1 = reinterpret_cast<const uint4*>(A + (size_t)arow1 * CH);

    #pragma unroll
    for (int k0 = 0; k0 < CH; k0 += 32) {
        const int fi = (k0 >> 3) + lg;
        uint4 r0 = ap0[fi];
        uint4 r1 = ap1[fi];
        r0.x = relu_pk(r0.x); r0.y = relu_pk(r0.y); r0.z = relu_pk(r0.z); r0.w = relu_pk(r0.w);
        r1.x = relu_pk(r1.x); r1.y = relu_pk(r1.y); r1.z = relu_pk(r1.z); r1.w = relu_pk(r1.w);
        s16x8 a0 = __builtin_bit_cast(s16x8, r0);
        s16x8 a1 = __builtin_bit_cast(s16x8, r1);
        #pragma unroll
        for (int n = 0; n < 8; ++n) {
            uint4 bv = WT[(size_t)fi * CH + n * 16 + l15];
            s16x8 b = __builtin_bit_cast(s16x8, bv);
            acc[0][n] = __builtin_amdgcn_mfma_f32_16x16x32_bf16(a0, b, acc[0][n], 0, 0, 0);
            acc[1][n] = __builtin_amdgcn_mfma_f32_16x16x32_bf16(a1, b, acc[1][n], 0, 0, 0);
        }
    }

    #pragma unroll
    for (int m = 0; m < 2; ++m) {
        #pragma unroll
        for (int i = 0; i < 4; ++i) {
            int row = block_row + m * 16 + lg * 4 + i;
            if (row < M) {
                float s = dinv[row];
                uint4 v;
                v.x = pk2bf(acc[m][0][i] * s, acc[m][1][i] * s);
                v.y = pk2bf(acc[m][2][i] * s, acc[m][3][i] * s);
                v.z = pk2bf(acc[m][4][i] * s, acc[m][5][i] * s);
                v.w = pk2bf(acc[m][6][i] * s, acc[m][7][i] * s);
                *reinterpret_cast<uint4*>(&C[(size_t)row * CH + l15 * 8]) = v;
            }
        }
    }
}

// ---------------- aggregation: out[d] = dinv[d]*(g[d] + sum g[src]) + bias ----------------
// g is bf16 permuted-col [node][128]; one wave per node, 1 uint (2 bf16) per lane.
// 8-deep software-pipelined gather: next batch's indices load while current gathers fly.
#define GATHER(cc) g[(size_t)__builtin_amdgcn_readfirstlane(cc) * 64 + lane]
template<bool OUT_BF16>
__launch_bounds__(256)
__global__ void aggregate_kernel(const unsigned int* __restrict__ g, const int2* __restrict__ row_range,
                                 const int* __restrict__ csr_src, const float* __restrict__ dinv,
                                 const float* __restrict__ bias, void* __restrict__ outp, int N) {
    const int gtid = blockIdx.x * blockDim.x + threadIdx.x;
    const int node = gtid >> 6;
    if (node >= N) return;
    const int lane = threadIdx.x & 63;

    unsigned int su = g[(size_t)node * 64 + lane];   // self-loop term
    const int2 rr = row_range[node];
    float ax = bf_lo(su);
    float ay = bf_hi(su);

    int j = rr.x;
    const int end = rr.y;

    if (j + 8 <= end) {
        int c0 = csr_src[j], c1 = csr_src[j+1], c2 = csr_src[j+2], c3 = csr_src[j+3];
        int c4 = csr_src[j+4], c5 = csr_src[j+5], c6 = csr_src[j+6], c7 = csr_src[j+7];
        j += 8;
        while (j + 8 <= end) {
            int n0 = csr_src[j], n1 = csr_src[j+1], n2 = csr_src[j+2], n3 = csr_src[j+3];
            int n4 = csr_src[j+4], n5 = csr_src[j+5], n6 = csr_src[j+6], n7 = csr_src[j+7];
            j += 8;
            unsigned int u0 = GATHER(c0), u1 = GATHER(c1), u2 = GATHER(c2), u3 = GATHER(c3);
            unsigned int u4 = GATHER(c4), u5 = GATHER(c5), u6 = GATHER(c6), u7 = GATHER(c7);
            ax += ((bf_lo(u0) + bf_lo(u1)) + (bf_lo(u2) + bf_lo(u3)))
                + ((bf_lo(u4) + bf_lo(u5)) + (bf_lo(u6) + bf_lo(u7)));
            ay += ((bf_hi(u0) + bf_hi(u1)) + (bf_hi(u2) + bf_hi(u3)))
                + ((bf_hi(u4) + bf_hi(u5)) + (bf_hi(u6) + bf_hi(u7)));
            c0 = n0; c1 = n1; c2 = n2; c3 = n3;
            c4 = n4; c5 = n5; c6 = n6; c7 = n7;
        }
        unsigned int u0 = GATHER(c0), u1 = GATHER(c1), u2 = GATHER(c2), u3 = GATHER(c3);
        unsigned int u4 = GATHER(c4), u5 = GATHER(c5), u6 = GATHER(c6), u7 = GATHER(c7);
        ax += ((bf_lo(u0) + bf_lo(u1)) + (bf_lo(u2) + bf_lo(u3)))
            + ((bf_lo(u4) + bf_lo(u5)) + (bf_lo(u6) + bf_lo(u7)));
        ay += ((bf_hi(u0) + bf_hi(u1)) + (bf_hi(u2) + bf_hi(u3)))
            + ((bf_hi(u4) + bf_hi(u5)) + (bf_hi(u6) + bf_hi(u7)));
    }
    for (; j + 2 <= end; j += 2) {
        int c0 = csr_src[j], c1 = csr_src[j+1];
        unsigned int u0 = GATHER(c0), u1 = GATHER(c1);
        ax += bf_lo(u0) + bf_lo(u1);
        ay += bf_hi(u0) + bf_hi(u1);
    }
    if (j < end) {
        int c0 = csr_src[j];
        unsigned int u0 = GATHER(c0);
        ax += bf_lo(u0);
        ay += bf_hi(u0);
    }

    const int cp0 = lane << 1;
    const int cp1 = cp0 | 1;
    const int c0 = (cp0 >> 3) + ((cp0 & 7) << 4);    // true cols
    const int c1 = (cp1 >> 3) + ((cp1 & 7) << 4);
    const float di = dinv[node];
    float ox = di * ax + bias[c0];
    float oy = di * ay + bias[c1];
    if (OUT_BF16) {
        ((unsigned int*)outp)[(size_t)node * 64 + lane] = pk2bf(ox, oy);
    } else {
        float* o = (float*)outp + (size_t)node * CH;
        o[c0] = ox;
        o[c1] = oy;
    }
}

extern "C" void kernel_launch(void* const* d_in, const int* in_sizes, int n_in,
                              void* d_out, int out_size, void* d_ws, size_t ws_size,
                              hipStream_t stream) {
    const float* x  = (const float*)d_in[0];
    const int*   ei = (const int*)d_in[1];
    const float* W1 = (const float*)d_in[2];
    const float* b1 = (const float*)d_in[3];
    const float* W2 = (const float*)d_in[4];
    const float* b2 = (const float*)d_in[5];
    float* out = (float*)d_out;

    const int N = in_sizes[0] / IN_CH_K;       // 100000
    const int E = in_sizes[1] / 2;             // 1600000
    const int* e_src = ei;
    const int* e_dst = ei + E;

    const int NB = (N + 255) >> 8;             // 391 coarse buckets
    const int NCHUNK = (E + CHUNK - 1) / CHUNK;

    char* w = (char*)d_ws;
    auto alloc = [&](size_t bytes) {
        char* p = w;
        w += (bytes + 255) & ~(size_t)255;
        return p;
    };
    int*   cursor    = (int*)  alloc((size_t)NB * 4);
    int2*  row_range = (int2*) alloc((size_t)N * 8);
    float* dinv      = (float*)alloc((size_t)N * 4);
    int*   csr_src   = (int*)  alloc((size_t)NB * BPAD * 4);
    uint4* w1t       = (uint4*)alloc((size_t)(IN_CH_K / 8) * CH * 16);
    uint4* w2t       = (uint4*)alloc((size_t)(CH / 8) * CH * 16);
    unsigned short* gbuf = (unsigned short*)alloc((size_t)N * CH * 2);  // g1 / g2
    unsigned short* abuf = (unsigned short*)alloc((size_t)N * CH * 2);  // a1
    int* binned = (int*)gbuf;   // aliases gbuf (8 MB < 25.6 MB): dead before gemm1 writes

    // ---- CSR build (padded bucket sort) + weight conversion ----
    init_cursor_kernel<<<(NB + 255) / 256, 256, 0, stream>>>(cursor, NB);
    bin_kernel<<<NCHUNK, 256, 0, stream>>>(e_src, e_dst, cursor, binned, E, NB);
    csr_bucket_kernel<<<NB, 256, 0, stream>>>(binned, cursor, row_range, csr_src, dinv, N);
    convert_w_kernel<false><<<(IN_CH_K / 8 * CH + 255) / 256, 256, 0, stream>>>(W1, w1t, IN_CH_K);
    convert_w_kernel<true><<<(CH / 8 * CH + 255) / 256, 256, 0, stream>>>(W2, w2t, CH);

    const int gemm_grid = (N + 127) / 128;
    const int agg_grid = (N * 64 + 255) / 256;

    // ---- layer 1 ----
    gemm1_mfma_kernel<<<gemm_grid, 256, 0, stream>>>(x, w1t, dinv, gbuf, N);
    aggregate_kernel<true><<<agg_grid, 256, 0, stream>>>((const unsigned int*)gbuf, row_range,
                                                         csr_src, dinv, b1, abuf, N);

    // ---- layer 2 ----
    gemm2_mfma_kernel<<<gemm_grid, 256, 0, stream>>>(abuf, w2t, dinv, gbuf, N);
    aggregate_kernel<false><<<agg_grid, 256, 0, stream>>>((const unsigned int*)gbuf, row_range,
                                                          csr_src, dinv, b2, out, N);
}